// Round 10
// baseline (233.906 us; speedup 1.0000x reference)
//
#include <hip/hip_runtime.h>
#include <math.h>

#define B_  128
#define E_  128
#define H2_ 512
#define H3_ 1536
#define L_  512
#define V_  50000
#define VL_ 50512   // V + L

typedef short bf16x8 __attribute__((ext_vector_type(8)));
typedef float f32x4 __attribute__((ext_vector_type(4)));

__device__ __forceinline__ float fast_tanh(float x) {
    float e = __expf(2.f * x);
    return 1.f - 2.f / (e + 1.f);
}
__device__ __forceinline__ float fast_sigmoid(float x) {
    return 1.f / (1.f + __expf(-x));
}
__device__ __forceinline__ short f2bf(float f) {
    unsigned u = __float_as_uint(f);
    u += 0x7fff + ((u >> 16) & 1);        // RNE
    return (short)(u >> 16);
}

// ---------------- gx & gh GEMMs, split-K -> PARTIAL buffers (no atomics) -------------
__global__ void k_gates(const int* __restrict__ ids, const float* __restrict__ tab,
                        const float* __restrict__ hidden,
                        const float* __restrict__ W_ih, const float* __restrict__ W_hh,
                        float* __restrict__ gxp, float* __restrict__ ghp) {
    __shared__ float As[32][36];
    __shared__ float Ws[32][36];
    int z = blockIdx.z;
    int which = (z < 2) ? 0 : 1;
    int kbeg  = which ? (z - 2) * 128 : z * 64;
    int kiter = which ? 4 : 2;
    const float* W = which ? W_hh : W_ih;
    int ldw = which ? H2_ : E_;
    float* C = which ? (ghp + (size_t)(z - 2) * B_ * H3_) : (gxp + (size_t)z * B_ * H3_);
    int bm = blockIdx.x * 32, bn = blockIdx.y * 32;
    int tid = threadIdx.x;
    int tm0 = (tid / 16) * 2, tn0 = (tid % 16) * 2;
    float acc[2][2] = {};
    for (int it = 0; it < kiter; ++it) {
        int k0 = kbeg + it * 32;
        for (int v = tid; v < 256; v += 256) {
            int m = v >> 3, q = (v & 7) << 2;
            int gm = bm + m;
            const float* arow = which ? (hidden + (size_t)gm * H2_)
                                      : (tab + (size_t)ids[gm] * E_);
            float4 x = *(const float4*)(arow + k0 + q);
            As[q+0][m] = x.x; As[q+1][m] = x.y; As[q+2][m] = x.z; As[q+3][m] = x.w;
        }
        for (int v = tid; v < 256; v += 256) {
            int n = v >> 3, q = (v & 7) << 2;
            float4 x = *(const float4*)(W + (size_t)(bn + n) * ldw + k0 + q);
            Ws[q+0][n] = x.x; Ws[q+1][n] = x.y; Ws[q+2][n] = x.z; Ws[q+3][n] = x.w;
        }
        __syncthreads();
        #pragma unroll
        for (int kk = 0; kk < 32; ++kk) {
            float a0 = As[kk][tm0], a1 = As[kk][tm0+1];
            float w0 = Ws[kk][tn0], w1 = Ws[kk][tn0+1];
            acc[0][0] += a0*w0; acc[0][1] += a0*w1;
            acc[1][0] += a1*w0; acc[1][1] += a1*w1;
        }
        __syncthreads();
    }
    #pragma unroll
    for (int i = 0; i < 2; ++i)
        #pragma unroll
        for (int j = 0; j < 2; ++j)
            C[(size_t)(bm+tm0+i) * H3_ + bn+tn0+j] = acc[i][j];
}

// ---------------- dsl GEMM: split-K 4, atomicAdd onto bias-init dsl ----------------
template<int BM, int BN, int BK, int TM, int TN, int SPLITK>
__global__ void gemm_atomic(const float* __restrict__ A, int lda,
                            const float* __restrict__ W, int ldw,
                            float* __restrict__ C, int ldc, int N, int K) {
    __shared__ float As[BK][BM + 4];
    __shared__ float Ws[BK][BN + 4];
    int bm = blockIdx.x * BM, bn = blockIdx.y * BN;
    int tid = threadIdx.x;
    constexpr int NT = BN / TN;
    int tm0 = (tid / NT) * TM;
    int tn0 = (tid % NT) * TN;
    int kchunk = K / SPLITK;
    int kbeg = blockIdx.z * kchunk;
    float acc[TM][TN] = {};
    for (int k0 = kbeg; k0 < kbeg + kchunk; k0 += BK) {
        #pragma unroll
        for (int v = tid; v < BM * BK / 4; v += 256) {
            int m = v / (BK / 4), q = (v % (BK / 4)) * 4;
            float4 x = *(const float4*)(A + (size_t)(bm + m) * lda + k0 + q);
            As[q+0][m] = x.x; As[q+1][m] = x.y; As[q+2][m] = x.z; As[q+3][m] = x.w;
        }
        #pragma unroll
        for (int v = tid; v < BN * BK / 4; v += 256) {
            int n = v / (BK / 4), q = (v % (BK / 4)) * 4;
            float4 x = *(const float4*)(W + (size_t)(bn + n) * ldw + k0 + q);
            Ws[q+0][n] = x.x; Ws[q+1][n] = x.y; Ws[q+2][n] = x.z; Ws[q+3][n] = x.w;
        }
        __syncthreads();
        #pragma unroll
        for (int kk = 0; kk < BK; ++kk) {
            float a[TM], w[TN];
            #pragma unroll
            for (int i = 0; i < TM; ++i) a[i] = As[kk][tm0 + i];
            #pragma unroll
            for (int j = 0; j < TN; ++j) w[j] = Ws[kk][tn0 + j];
            #pragma unroll
            for (int i = 0; i < TM; ++i)
                #pragma unroll
                for (int j = 0; j < TN; ++j) acc[i][j] += a[i] * w[j];
        }
        __syncthreads();
    }
    #pragma unroll
    for (int i = 0; i < TM; ++i)
        #pragma unroll
        for (int j = 0; j < TN; ++j)
            atomicAdd(&C[(size_t)(bm+tm0+i) * ldc + bn+tn0+j], acc[i][j]);
}

// ---------------- GRU: reduce gate partials + biases; init dsl=b_ds, rsum8=0 ---------
__global__ void k_gru(const float* __restrict__ gxp, const float* __restrict__ ghp,
                      const float* __restrict__ b_ih, const float* __restrict__ b_hh,
                      const float* __restrict__ h0, const float* __restrict__ b_ds,
                      float* __restrict__ comb, float* __restrict__ hout,
                      float* __restrict__ dsl, float* __restrict__ rsum8) {
    int idx = blockIdx.x * blockDim.x + threadIdx.x;  // B*H2 = 65536
    int b = idx >> 9, h = idx & 511;
    const float* gx0 = gxp + (size_t)b * H3_;
    const float* gx1 = gx0 + (size_t)B_ * H3_;
    float xr = gx0[h]         + gx1[h]         + b_ih[h];
    float xz = gx0[H2_+h]     + gx1[H2_+h]     + b_ih[H2_+h];
    float xn = gx0[2*H2_+h]   + gx1[2*H2_+h]   + b_ih[2*H2_+h];
    float hr = b_hh[h], hz = b_hh[H2_+h], hn = b_hh[2*H2_+h];
    #pragma unroll
    for (int z = 0; z < 4; ++z) {
        const float* g = ghp + ((size_t)z * B_ + b) * H3_;
        hr += g[h]; hz += g[H2_+h]; hn += g[2*H2_+h];
    }
    float r = fast_sigmoid(xr + hr);
    float zz = fast_sigmoid(xz + hz);
    float n = fast_tanh(xn + r * hn);
    float hv = (1.f - zz) * n + zz * h0[idx];
    comb[b * (2 * H2_) + h] = hv;
    hout[idx] = hv;
    dsl[idx] = b_ds[h];                 // bias init for atomic split-K dsl
    if (idx < 1024) rsum8[idx] = 0.f;
}

// ---------------- FUSED attention: scores + softmax(b) + context partials ------------
// 128 blocks x 1024 thr; block owns l in [blk*4, blk*4+4). enc read once from HBM.
__global__ __launch_bounds__(1024, 4)
void k_attn(const float* __restrict__ enc, const float* __restrict__ dsl,
            const float* __restrict__ w_h, const float* __restrict__ att_v,
            float* __restrict__ attn, float* __restrict__ pctx) {
    __shared__ float sp[8][16][2];
    __shared__ float attn_lds[128];
    int t = threadIdx.x;
    int g = t >> 7;                 // b-group 0..7
    int h4 = t & 127;               // float4 index over h
    int lane = t & 63;
    int w2 = (t >> 6) & 1;          // wave-half within group
    float4 wv = ((const float4*)w_h)[h4];
    float4 vv = ((const float4*)att_v)[h4];
    float4 acc[16];
    #pragma unroll
    for (int i = 0; i < 16; ++i) acc[i] = make_float4(0.f, 0.f, 0.f, 0.f);
    int l0 = blockIdx.x << 2;
    for (int lj = 0; lj < 4; ++lj) {
        int l = l0 + lj;
        // phase 1: per-b scores (group g, slot i -> b = g + 8i)
        #pragma unroll
        for (int i = 0; i < 16; ++i) {
            int b = g + (i << 3);
            float4 e = ((const float4*)enc)[((size_t)l * B_ + b) * 128 + h4];
            float4 d = ((const float4*)dsl)[b * 128 + h4];
            float p;
            p  = vv.x * fast_tanh(wv.x * e.x + d.x);
            p += vv.y * fast_tanh(wv.y * e.y + d.y);
            p += vv.z * fast_tanh(wv.z * e.z + d.z);
            p += vv.w * fast_tanh(wv.w * e.w + d.w);
            #pragma unroll
            for (int o = 32; o; o >>= 1) p += __shfl_xor(p, o);
            if (lane == 0) sp[g][i][w2] = p;
        }
        __syncthreads();
        // softmax over b (wave 0)
        if (t < 64) {
            int b1 = t + 64;
            float s0 = sp[t & 7][t >> 3][0] + sp[t & 7][t >> 3][1];
            float s1 = sp[t & 7][(t >> 3) + 8][0] + sp[t & 7][(t >> 3) + 8][1];
            float m = fmaxf(s0, s1);
            #pragma unroll
            for (int o = 32; o; o >>= 1) m = fmaxf(m, __shfl_xor(m, o));
            float e0 = __expf(s0 - m), e1 = __expf(s1 - m);
            float tt = e0 + e1;
            #pragma unroll
            for (int o = 32; o; o >>= 1) tt += __shfl_xor(tt, o);
            float inv = 1.f / tt;
            attn_lds[t]  = e0 * inv;
            attn_lds[b1] = e1 * inv;
            attn[l * B_ + t]  = e0 * inv;
            attn[l * B_ + b1] = e1 * inv;
        }
        __syncthreads();
        // phase 2: ctx accumulate (enc re-read hits L2/L3)
        #pragma unroll
        for (int i = 0; i < 16; ++i) {
            int b = g + (i << 3);
            float4 e = ((const float4*)enc)[((size_t)l * B_ + b) * 128 + h4];
            float a = attn_lds[b];
            acc[i].x += a * e.x; acc[i].y += a * e.y;
            acc[i].z += a * e.z; acc[i].w += a * e.w;
        }
    }
    // store ctx partials for this block
    #pragma unroll
    for (int i = 0; i < 16; ++i) {
        int b = g + (i << 3);
        ((float4*)pctx)[(size_t)blockIdx.x * 16384 + b * 128 + h4] = acc[i];
    }
}

// ---------------- ctx reduce + p_gen + hid mini-GEMM: 128 blocks x 128 thr -----------
__global__ void k_cph(const float* __restrict__ pctx, const int* __restrict__ ids,
                      const float* __restrict__ tab, const float* __restrict__ W_ptr,
                      const float* __restrict__ b_ptr, const float* __restrict__ W_oh,
                      const float* __restrict__ b_oh,
                      float* __restrict__ comb, float* __restrict__ pgen,
                      float* __restrict__ hid) {
    __shared__ float cmb[1024];
    __shared__ float red[128];
    int b = blockIdx.x, tid = threadIdx.x;   // tid = h4 slot / n index
    float4 c = make_float4(0.f, 0.f, 0.f, 0.f);
    #pragma unroll 8
    for (int z = 0; z < 128; ++z) {
        float4 x = ((const float4*)pctx)[(size_t)z * 16384 + b * 128 + tid];
        c.x += x.x; c.y += x.y; c.z += x.z; c.w += x.w;
    }
    ((float4*)(comb + b * (2 * H2_) + H2_))[tid] = c;
    ((float4*)(cmb + H2_))[tid] = c;
    float4 hn = ((const float4*)(comb + b * (2 * H2_)))[tid];
    ((float4*)cmb)[tid] = hn;
    // p_gen dot
    const float4* wp = (const float4*)W_ptr;
    float4 wh = wp[tid], wc = wp[128 + tid];
    float s = hn.x*wh.x + hn.y*wh.y + hn.z*wh.z + hn.w*wh.w
            + c.x*wc.x + c.y*wc.y + c.z*wc.z + c.w*wc.w;
    if (tid < 32) {
        float4 ev = ((const float4*)(tab + (size_t)ids[b] * E_))[tid];
        float4 we = wp[256 + tid];
        s += ev.x*we.x + ev.y*we.y + ev.z*we.z + ev.w*we.w;
    }
    red[tid] = s;
    __syncthreads();
    if (tid < 64) {
        float tt = red[tid] + red[tid + 64];
        #pragma unroll
        for (int o = 32; o; o >>= 1) tt += __shfl_xor(tt, o);
        if (tid == 0) pgen[b] = fast_sigmoid(tt + b_ptr[0]);
    }
    // hid[b][n]: n = tid, dot over 1024 (cmb LDS broadcast, W_oh row stream)
    float acc = b_oh[tid];
    const float4* wr = (const float4*)(W_oh + (size_t)tid * (2 * H2_));
    #pragma unroll 8
    for (int k = 0; k < 256; ++k) {
        float4 ww = wr[k];
        acc += cmb[k*4+0]*ww.x + cmb[k*4+1]*ww.y + cmb[k*4+2]*ww.z + cmb[k*4+3]*ww.w;
    }
    hid[b * E_ + tid] = acc;
}

// ---------------- vocab MFMA pass 1: rsum8 only ----------------
__global__ void k_vsum(const float* __restrict__ hid, const float* __restrict__ Wov,
                       const float* __restrict__ bov, float* __restrict__ rsum8) {
    __shared__ float sm[4][128];
    int L = threadIdx.x & 63, w = threadIdx.x >> 6;
    int lrow = L & 15, lk = L >> 4;
    int n0 = blockIdx.x * 128 + w * 32;
    bf16x8 bfr[2][4];
    #pragma unroll
    for (int nt = 0; nt < 2; ++nt) {
        int n = n0 + nt * 16 + lrow;
        #pragma unroll
        for (int kk = 0; kk < 4; ++kk) {
            bf16x8 f;
            if (n < V_) {
                const float* p = Wov + (size_t)n * 128 + kk * 32 + lk * 8;
                float4 x = *(const float4*)p, y = *(const float4*)(p + 4);
                f[0]=f2bf(x.x); f[1]=f2bf(x.y); f[2]=f2bf(x.z); f[3]=f2bf(x.w);
                f[4]=f2bf(y.x); f[5]=f2bf(y.y); f[6]=f2bf(y.z); f[7]=f2bf(y.w);
            } else {
                #pragma unroll
                for (int j = 0; j < 8; ++j) f[j] = 0;
            }
            bfr[nt][kk] = f;
        }
    }
    f32x4 acc[8][2] = {};
    #pragma unroll
    for (int mt = 0; mt < 8; ++mt) {
        bf16x8 afr[4];
        #pragma unroll
        for (int kk = 0; kk < 4; ++kk) {
            const float* p = hid + (size_t)(mt * 16 + lrow) * 128 + kk * 32 + lk * 8;
            float4 x = *(const float4*)p, y = *(const float4*)(p + 4);
            bf16x8 f;
            f[0]=f2bf(x.x); f[1]=f2bf(x.y); f[2]=f2bf(x.z); f[3]=f2bf(x.w);
            f[4]=f2bf(y.x); f[5]=f2bf(y.y); f[6]=f2bf(y.z); f[7]=f2bf(y.w);
            afr[kk] = f;
        }
        #pragma unroll
        for (int nt = 0; nt < 2; ++nt)
            #pragma unroll
            for (int kk = 0; kk < 4; ++kk)
                acc[mt][nt] = __builtin_amdgcn_mfma_f32_16x16x32_bf16(
                    afr[kk], bfr[nt][kk], acc[mt][nt], 0, 0, 0);
    }
    float bv[2];
    #pragma unroll
    for (int nt = 0; nt < 2; ++nt) {
        int n = n0 + nt * 16 + lrow;
        bv[nt] = (n < V_) ? bov[n] : 0.f;
    }
    float rs[8][4];
    #pragma unroll
    for (int mt = 0; mt < 8; ++mt) {
        #pragma unroll
        for (int r = 0; r < 4; ++r) rs[mt][r] = 0.f;
        #pragma unroll
        for (int nt = 0; nt < 2; ++nt) {
            int n = n0 + nt * 16 + lrow;
            if (n < V_) {
                #pragma unroll
                for (int r = 0; r < 4; ++r)
                    rs[mt][r] += __expf(acc[mt][nt][r] + bv[nt]);
            }
        }
    }
    #pragma unroll
    for (int o = 1; o < 16; o <<= 1)
        #pragma unroll
        for (int mt = 0; mt < 8; ++mt)
            #pragma unroll
            for (int r = 0; r < 4; ++r) rs[mt][r] += __shfl_xor(rs[mt][r], o);
    if (lrow == 0) {
        #pragma unroll
        for (int mt = 0; mt < 8; ++mt)
            #pragma unroll
            for (int r = 0; r < 4; ++r)
                sm[w][mt * 16 + lk * 4 + r] = rs[mt][r];
    }
    __syncthreads();
    if (threadIdx.x < 128) {
        float p = sm[0][threadIdx.x] + sm[1][threadIdx.x]
                + sm[2][threadIdx.x] + sm[3][threadIdx.x];
        atomicAdd(&rsum8[(blockIdx.x & 7) * 128 + threadIdx.x], p);
    }
}

// ---------------- vocab MFMA pass 2: recompute, scale, write (+pad) ----------------
__global__ void k_vwrite(const float* __restrict__ hid, const float* __restrict__ Wov,
                         const float* __restrict__ bov, const float* __restrict__ pgen,
                         const float* __restrict__ rsum8, float* __restrict__ out) {
    __shared__ float scs[128];
    if (blockIdx.x == 391) {     // pad-zero group
        for (int i = threadIdx.x; i < B_ * (L_ / 4); i += 256) {
            int b = i >> 7, k = i & 127;
            ((float4*)(out + (size_t)b * VL_ + V_))[k] = make_float4(0.f,0.f,0.f,0.f);
        }
        return;
    }
    if (threadIdx.x < 128) {
        float s = 0.f;
        #pragma unroll
        for (int j = 0; j < 8; ++j) s += rsum8[j * 128 + threadIdx.x];
        scs[threadIdx.x] = pgen[threadIdx.x] / s;
    }
    __syncthreads();
    int L = threadIdx.x & 63, w = threadIdx.x >> 6;
    int lrow = L & 15, lk = L >> 4;
    int n0 = blockIdx.x * 128 + w * 32;
    bf16x8 bfr[2][4];
    #pragma unroll
    for (int nt = 0; nt < 2; ++nt) {
        int n = n0 + nt * 16 + lrow;
        #pragma unroll
        for (int kk = 0; kk < 4; ++kk) {
            bf16x8 f;
            if (n < V_) {
                const float* p = Wov + (size_t)n * 128 + kk * 32 + lk * 8;
                float4 x = *(const float4*)p, y = *(const float4*)(p + 4);
                f[0]=f2bf(x.x); f[1]=f2bf(x.y); f[2]=f2bf(x.z); f[3]=f2bf(x.w);
                f[4]=f2bf(y.x); f[5]=f2bf(y.y); f[6]=f2bf(y.z); f[7]=f2bf(y.w);
            } else {
                #pragma unroll
                for (int j = 0; j < 8; ++j) f[j] = 0;
            }
            bfr[nt][kk] = f;
        }
    }
    f32x4 acc[8][2] = {};
    #pragma unroll
    for (int mt = 0; mt < 8; ++mt) {
        bf16x8 afr[4];
        #pragma unroll
        for (int kk = 0; kk < 4; ++kk) {
            const float* p = hid + (size_t)(mt * 16 + lrow) * 128 + kk * 32 + lk * 8;
            float4 x = *(const float4*)p, y = *(const float4*)(p + 4);
            bf16x8 f;
            f[0]=f2bf(x.x); f[1]=f2bf(x.y); f[2]=f2bf(x.z); f[3]=f2bf(x.w);
            f[4]=f2bf(y.x); f[5]=f2bf(y.y); f[6]=f2bf(y.z); f[7]=f2bf(y.w);
            afr[kk] = f;
        }
        #pragma unroll
        for (int nt = 0; nt < 2; ++nt)
            #pragma unroll
            for (int kk = 0; kk < 4; ++kk)
                acc[mt][nt] = __builtin_amdgcn_mfma_f32_16x16x32_bf16(
                    afr[kk], bfr[nt][kk], acc[mt][nt], 0, 0, 0);
    }
    float bv[2];
    #pragma unroll
    for (int nt = 0; nt < 2; ++nt) {
        int n = n0 + nt * 16 + lrow;
        bv[nt] = (n < V_) ? bov[n] : 0.f;
    }
    #pragma unroll
    for (int mt = 0; mt < 8; ++mt) {
        #pragma unroll
        for (int nt = 0; nt < 2; ++nt) {
            int n = n0 + nt * 16 + lrow;
            if (n < V_) {
                #pragma unroll
                for (int r = 0; r < 4; ++r) {
                    int row = mt * 16 + lk * 4 + r;
                    out[(size_t)row * VL_ + n] =
                        __expf(acc[mt][nt][r] + bv[nt]) * scs[row];
                }
            }
        }
    }
}

// ---------------- scatter copy distribution ----------------
__global__ void k_scatter(float* __restrict__ out, const int* __restrict__ full_input,
                          const float* __restrict__ attn, const float* __restrict__ pgen) {
    int idx = blockIdx.x * blockDim.x + threadIdx.x;  // L*B = 65536
    int b = idx & 127;
    int tok = full_input[idx];
    atomicAdd(&out[(size_t)b * VL_ + tok], (1.f - pgen[b]) * attn[idx]);
}

extern "C" void kernel_launch(void* const* d_in, const int* in_sizes, int n_in,
                              void* d_out, int out_size, void* d_ws, size_t ws_size,
                              hipStream_t stream) {
    const int*   input_ids = (const int*)d_in[0];
    const float* hidden    = (const float*)d_in[1];
    const float* enc       = (const float*)d_in[2];
    const int*   full_in   = (const int*)d_in[3];
    const float* emb_tab   = (const float*)d_in[4];
    const float* W_ih      = (const float*)d_in[5];
    const float* W_hh      = (const float*)d_in[6];
    const float* b_ih      = (const float*)d_in[7];
    const float* b_hh      = (const float*)d_in[8];
    const float* W_ds      = (const float*)d_in[9];
    const float* b_ds      = (const float*)d_in[10];
    const float* w_h       = (const float*)d_in[11];
    const float* att_v     = (const float*)d_in[12];
    const float* W_oh      = (const float*)d_in[13];
    const float* b_oh      = (const float*)d_in[14];
    const float* W_ov      = (const float*)d_in[15];
    const float* b_ov      = (const float*)d_in[16];
    const float* W_ptr     = (const float*)d_in[17];
    const float* b_ptr     = (const float*)d_in[18];

    float* out = (float*)d_out;
    float* p_final = out;                                  // [B, VL]
    float* h_out   = out + (size_t)B_ * VL_;               // [B, H2]
    float* attn    = out + (size_t)B_ * VL_ + B_ * H2_;    // [L, B]

    float* ws = (float*)d_ws;
    float* gxp    = ws;             // 2 * 196608 = 393216
    float* ghp    = gxp + 393216;   // 4 * 196608 = 786432
    float* comb   = ghp + 786432;   // 131072
    float* dsl    = comb + 131072;  // 65536
    float* hid    = dsl + 65536;    // 16384
    float* pgen   = hid + 16384;    // 128
    float* rsum8  = pgen + 128;     // 1024
    float* pctx   = rsum8 + 1024;   // 128 * 65536 = 8388608 (33.5 MB)

    // 1. gate GEMMs -> partials
    k_gates<<<dim3(4,48,6), dim3(256), 0, stream>>>(input_ids, emb_tab, hidden,
                                                    W_ih, W_hh, gxp, ghp);
    // 2. GRU -> h_new; dsl = b_ds; rsum8 = 0
    k_gru<<<dim3(256), dim3(256), 0, stream>>>(gxp, ghp, b_ih, b_hh, hidden, b_ds,
                                               comb, h_out, dsl, rsum8);
    // 3. dsl += h_new @ W_ds^T (split-K 4, atomic)
    gemm_atomic<32,32,32,2,2,4><<<dim3(4,16,4), dim3(256), 0, stream>>>(
        comb, 2*H2_, W_ds, H2_, dsl, H2_, H2_, H2_);
    // 4. FUSED attention: scores + softmax + ctx partials (enc once)
    k_attn<<<dim3(L_/4), dim3(1024), 0, stream>>>(enc, dsl, w_h, att_v, attn, pctx);
    // 5. ctx reduce + p_gen + hid
    k_cph<<<dim3(B_), dim3(128), 0, stream>>>(pctx, input_ids, emb_tab, W_ptr, b_ptr,
                                              W_oh, b_oh, comb, pgen, hid);
    // 6. vocab pass 1: rsum8
    k_vsum<<<dim3(391), dim3(256), 0, stream>>>(hid, W_ov, b_ov, rsum8);
    // 7. vocab pass 2: scale + write (+ pad zero)
    k_vwrite<<<dim3(392), dim3(256), 0, stream>>>(hid, W_ov, b_ov, pgen, rsum8, p_final);
    // 8. scatter
    k_scatter<<<dim3(L_*B_/256), dim3(256), 0, stream>>>(p_final, full_in, attn, pgen);
}

// Round 11
// 159.370 us; speedup vs baseline: 1.4677x; 1.4677x over previous
//
#include <hip/hip_runtime.h>
#include <math.h>

#define B_  128
#define E_  128
#define H2_ 512
#define H3_ 1536
#define L_  512
#define V_  50000
#define VL_ 50512   // V + L

typedef short bf16x8 __attribute__((ext_vector_type(8)));
typedef float f32x4 __attribute__((ext_vector_type(4)));

__device__ __forceinline__ float fast_tanh(float x) {
    float e = __expf(2.f * x);
    return 1.f - 2.f / (e + 1.f);
}
__device__ __forceinline__ float fast_sigmoid(float x) {
    return 1.f / (1.f + __expf(-x));
}
__device__ __forceinline__ short f2bf(float f) {
    unsigned u = __float_as_uint(f);
    u += 0x7fff + ((u >> 16) & 1);        // RNE
    return (short)(u >> 16);
}

// ---------------- gx & gh GEMMs, split-K -> PARTIAL buffers (no atomics) -------------
__global__ void k_gates(const int* __restrict__ ids, const float* __restrict__ tab,
                        const float* __restrict__ hidden,
                        const float* __restrict__ W_ih, const float* __restrict__ W_hh,
                        float* __restrict__ gxp, float* __restrict__ ghp) {
    __shared__ float As[32][36];
    __shared__ float Ws[32][36];
    int z = blockIdx.z;
    int which = (z < 2) ? 0 : 1;
    int kbeg  = which ? (z - 2) * 128 : z * 64;
    int kiter = which ? 4 : 2;
    const float* W = which ? W_hh : W_ih;
    int ldw = which ? H2_ : E_;
    float* C = which ? (ghp + (size_t)(z - 2) * B_ * H3_) : (gxp + (size_t)z * B_ * H3_);
    int bm = blockIdx.x * 32, bn = blockIdx.y * 32;
    int tid = threadIdx.x;
    int tm0 = (tid / 16) * 2, tn0 = (tid % 16) * 2;
    float acc[2][2] = {};
    for (int it = 0; it < kiter; ++it) {
        int k0 = kbeg + it * 32;
        for (int v = tid; v < 256; v += 256) {
            int m = v >> 3, q = (v & 7) << 2;
            int gm = bm + m;
            const float* arow = which ? (hidden + (size_t)gm * H2_)
                                      : (tab + (size_t)ids[gm] * E_);
            float4 x = *(const float4*)(arow + k0 + q);
            As[q+0][m] = x.x; As[q+1][m] = x.y; As[q+2][m] = x.z; As[q+3][m] = x.w;
        }
        for (int v = tid; v < 256; v += 256) {
            int n = v >> 3, q = (v & 7) << 2;
            float4 x = *(const float4*)(W + (size_t)(bn + n) * ldw + k0 + q);
            Ws[q+0][n] = x.x; Ws[q+1][n] = x.y; Ws[q+2][n] = x.z; Ws[q+3][n] = x.w;
        }
        __syncthreads();
        #pragma unroll
        for (int kk = 0; kk < 32; ++kk) {
            float a0 = As[kk][tm0], a1 = As[kk][tm0+1];
            float w0 = Ws[kk][tn0], w1 = Ws[kk][tn0+1];
            acc[0][0] += a0*w0; acc[0][1] += a0*w1;
            acc[1][0] += a1*w0; acc[1][1] += a1*w1;
        }
        __syncthreads();
    }
    #pragma unroll
    for (int i = 0; i < 2; ++i)
        #pragma unroll
        for (int j = 0; j < 2; ++j)
            C[(size_t)(bm+tm0+i) * H3_ + bn+tn0+j] = acc[i][j];
}

// ---------------- generic tiled GEMM, split-K: partial-store or atomic ----------------
template<int BM, int BN, int BK, int TM, int TN, int SPLITK, bool ATOMIC>
__global__ void gemm_t(const float* __restrict__ A, int lda,
                       const float* __restrict__ W, int ldw,
                       float* __restrict__ C, int ldc,
                       int N, int K, int partElems) {
    __shared__ float As[BK][BM + 4];
    __shared__ float Ws[BK][BN + 4];
    int bm = blockIdx.x * BM, bn = blockIdx.y * BN;
    int tid = threadIdx.x;
    constexpr int NT = BN / TN;
    int tm0 = (tid / NT) * TM;
    int tn0 = (tid % NT) * TN;
    int kchunk = K / SPLITK;
    int kbeg = blockIdx.z * kchunk;
    float acc[TM][TN] = {};
    for (int k0 = kbeg; k0 < kbeg + kchunk; k0 += BK) {
        #pragma unroll
        for (int v = tid; v < BM * BK / 4; v += 256) {
            int m = v / (BK / 4), q = (v % (BK / 4)) * 4;
            float4 x = *(const float4*)(A + (size_t)(bm + m) * lda + k0 + q);
            As[q+0][m] = x.x; As[q+1][m] = x.y; As[q+2][m] = x.z; As[q+3][m] = x.w;
        }
        #pragma unroll
        for (int v = tid; v < BN * BK / 4; v += 256) {
            int n = v / (BK / 4), q = (v % (BK / 4)) * 4;
            float4 x = *(const float4*)(W + (size_t)(bn + n) * ldw + k0 + q);
            Ws[q+0][n] = x.x; Ws[q+1][n] = x.y; Ws[q+2][n] = x.z; Ws[q+3][n] = x.w;
        }
        __syncthreads();
        #pragma unroll
        for (int kk = 0; kk < BK; ++kk) {
            float a[TM], w[TN];
            #pragma unroll
            for (int i = 0; i < TM; ++i) a[i] = As[kk][tm0 + i];
            #pragma unroll
            for (int j = 0; j < TN; ++j) w[j] = Ws[kk][tn0 + j];
            #pragma unroll
            for (int i = 0; i < TM; ++i)
                #pragma unroll
                for (int j = 0; j < TN; ++j) acc[i][j] += a[i] * w[j];
        }
        __syncthreads();
    }
    float* Cz = ATOMIC ? C : (C + (size_t)blockIdx.z * partElems);
    #pragma unroll
    for (int i = 0; i < TM; ++i)
        #pragma unroll
        for (int j = 0; j < TN; ++j) {
            if (ATOMIC) atomicAdd(&Cz[(size_t)(bm+tm0+i) * ldc + bn+tn0+j], acc[i][j]);
            else        Cz[(size_t)(bm+tm0+i) * ldc + bn+tn0+j] = acc[i][j];
        }
}

// ---------------- GRU: reduce gate partials + biases; init hid/rsum8 ----------------
__global__ void k_gru(const float* __restrict__ gxp, const float* __restrict__ ghp,
                      const float* __restrict__ b_ih, const float* __restrict__ b_hh,
                      const float* __restrict__ h0, const float* __restrict__ b_oh,
                      float* __restrict__ comb, float* __restrict__ hout,
                      float* __restrict__ hid, float* __restrict__ rsum8) {
    int idx = blockIdx.x * blockDim.x + threadIdx.x;  // B*H2 = 65536
    int b = idx >> 9, h = idx & 511;
    const float* gx0 = gxp + (size_t)b * H3_;
    const float* gx1 = gx0 + (size_t)B_ * H3_;
    float xr = gx0[h]         + gx1[h]         + b_ih[h];
    float xz = gx0[H2_+h]     + gx1[H2_+h]     + b_ih[H2_+h];
    float xn = gx0[2*H2_+h]   + gx1[2*H2_+h]   + b_ih[2*H2_+h];
    float hr = b_hh[h], hz = b_hh[H2_+h], hn = b_hh[2*H2_+h];
    #pragma unroll
    for (int z = 0; z < 4; ++z) {
        const float* g = ghp + ((size_t)z * B_ + b) * H3_;
        hr += g[h]; hz += g[H2_+h]; hn += g[2*H2_+h];
    }
    float r = fast_sigmoid(xr + hr);
    float zz = fast_sigmoid(xz + hz);
    float n = fast_tanh(xn + r * hn);
    float hv = (1.f - zz) * n + zz * h0[idx];
    comb[b * (2 * H2_) + h] = hv;
    hout[idx] = hv;
    if (idx < B_ * E_) hid[idx] = b_oh[idx & 127];   // split-K atomic target init
    if (idx < 1024)    rsum8[idx] = 0.f;
}

// ---------------- attention scores: one wave = 8 l's x same b; dsl from partials -----
__global__ void k_scores(const float* __restrict__ enc, const float* __restrict__ dslp,
                         const float* __restrict__ b_ds,
                         const float* __restrict__ w_h, const float* __restrict__ att_v,
                         float* __restrict__ scores) {
    int wid = (blockIdx.x << 2) + (threadIdx.x >> 6);  // 8192 waves
    int lane = threadIdx.x & 63;
    int b = wid & 127, lg = wid >> 7;                  // 64 l-groups of 8
    int l0 = lg << 3;
    const float4* w4 = (const float4*)w_h;
    const float4* v4 = (const float4*)att_v;
    const float4* bd4 = (const float4*)b_ds;
    float4 d0 = bd4[lane], d1 = bd4[lane + 64];
    #pragma unroll
    for (int z = 0; z < 4; ++z) {
        const float4* dp = (const float4*)(dslp + (size_t)z * B_ * H2_ + b * H2_);
        float4 p0 = dp[lane], p1 = dp[lane + 64];
        d0.x += p0.x; d0.y += p0.y; d0.z += p0.z; d0.w += p0.w;
        d1.x += p1.x; d1.y += p1.y; d1.z += p1.z; d1.w += p1.w;
    }
    float4 w0 = w4[lane], w1 = w4[lane + 64];
    float4 v0 = v4[lane], v1 = v4[lane + 64];
    float4 e0[8], e1[8];
    #pragma unroll
    for (int q = 0; q < 8; ++q) {
        const float4* e4 = (const float4*)(enc + ((size_t)((l0 + q) * B_ + b)) * H2_);
        e0[q] = e4[lane];
        e1[q] = e4[lane + 64];
    }
    float s[8];
    #pragma unroll
    for (int q = 0; q < 8; ++q) {
        float t;
        t  = v0.x * fast_tanh(w0.x * e0[q].x + d0.x);
        t += v0.y * fast_tanh(w0.y * e0[q].y + d0.y);
        t += v0.z * fast_tanh(w0.z * e0[q].z + d0.z);
        t += v0.w * fast_tanh(w0.w * e0[q].w + d0.w);
        t += v1.x * fast_tanh(w1.x * e1[q].x + d1.x);
        t += v1.y * fast_tanh(w1.y * e1[q].y + d1.y);
        t += v1.z * fast_tanh(w1.z * e1[q].z + d1.z);
        t += v1.w * fast_tanh(w1.w * e1[q].w + d1.w);
        s[q] = t;
    }
    #pragma unroll
    for (int q = 0; q < 8; ++q) {
        float t = s[q];
        #pragma unroll
        for (int o = 32; o; o >>= 1) t += __shfl_xor(t, o);
        if (lane == 0) scores[(l0 + q) * B_ + b] = t;
    }
}

// ---------------- FUSED softmax + context partials (+ attn write by b==0 blocks) -----
// grid (128 b, 8 lchunks) x 128 thr; 32KB scores tile in LDS per block.
__global__ void k_sctx(const float* __restrict__ enc, const float* __restrict__ scores,
                       float* __restrict__ attn, float* __restrict__ ctxp) {
    __shared__ float sa[64 * 128];     // scores -> attn in place
    int b = blockIdx.x, ly = blockIdx.y;
    int t = threadIdx.x;               // 128
    int l0 = ly << 6;
    float4* sa4 = (float4*)sa;
    const float4* sc4 = (const float4*)(scores + l0 * B_);
    #pragma unroll
    for (int i = t; i < 64 * 32; i += 128) sa4[i] = sc4[i];
    __syncthreads();
    // softmax over b for each l: thread pair (l = t>>1, half = t&1)
    {
        int l = t >> 1, half = t & 1;
        float* row = sa + l * 128 + half * 64;
        float m = -1e30f;
        #pragma unroll 8
        for (int j = 0; j < 64; ++j) m = fmaxf(m, row[j]);
        m = fmaxf(m, __shfl_xor(m, 1));
        float s = 0.f;
        #pragma unroll 8
        for (int j = 0; j < 64; ++j) s += __expf(row[j] - m);
        s += __shfl_xor(s, 1);
        float inv = 1.f / s;
        #pragma unroll 8
        for (int j = 0; j < 64; ++j) row[j] = __expf(row[j] - m) * inv;
    }
    __syncthreads();
    if (b == 0) {   // one b-block per lchunk writes attn output
        float4* a4 = (float4*)(attn + l0 * B_);
        #pragma unroll
        for (int i = t; i < 64 * 32; i += 128) a4[i] = sa4[i];
    }
    // context accumulate over this lchunk
    const float4* e = (const float4*)(enc + ((size_t)l0 * B_ + b) * H2_) + t;
    float4 c = make_float4(0.f, 0.f, 0.f, 0.f);
    #pragma unroll 8
    for (int i = 0; i < 64; ++i) {
        float4 x = e[(size_t)i * (B_ * H2_ / 4)];
        float a = sa[i * 128 + b];
        c.x += a * x.x; c.y += a * x.y; c.z += a * x.z; c.w += a * x.w;
    }
    ((float4*)(ctxp + ((size_t)ly * B_ + b) * H2_))[t] = c;
}

// ---------------- ctx reduce + p_gen: 128 blocks x 128 thr ----------------
__global__ void k_ctxpgen(const float* __restrict__ ctxp, const int* __restrict__ ids,
                          const float* __restrict__ tab, const float* __restrict__ W_ptr,
                          const float* __restrict__ b_ptr,
                          float* __restrict__ comb, float* __restrict__ pgen) {
    __shared__ float red[128];
    int b = blockIdx.x, tid = threadIdx.x;   // h4 = tid
    float4 c = make_float4(0.f, 0.f, 0.f, 0.f);
    #pragma unroll
    for (int z = 0; z < 8; ++z) {
        float4 x = ((const float4*)(ctxp + ((size_t)z * B_ + b) * H2_))[tid];
        c.x += x.x; c.y += x.y; c.z += x.z; c.w += x.w;
    }
    ((float4*)(comb + b * (2 * H2_) + H2_))[tid] = c;
    const float4* wp = (const float4*)W_ptr;
    float4 wc = wp[128 + tid];
    float s = c.x * wc.x + c.y * wc.y + c.z * wc.z + c.w * wc.w;
    float4 hv = ((const float4*)(comb + b * (2 * H2_)))[tid];
    float4 wh = wp[tid];
    s += hv.x * wh.x + hv.y * wh.y + hv.z * wh.z + hv.w * wh.w;
    if (tid < 32) {
        float4 ev = ((const float4*)(tab + (size_t)ids[b] * E_))[tid];
        float4 we = wp[256 + tid];
        s += ev.x * we.x + ev.y * we.y + ev.z * we.z + ev.w * we.w;
    }
    red[tid] = s;
    __syncthreads();
    if (tid < 64) {
        float t = red[tid] + red[tid + 64];
        #pragma unroll
        for (int o = 32; o; o >>= 1) t += __shfl_xor(t, o);
        if (tid == 0) pgen[b] = fast_sigmoid(t + b_ptr[0]);
    }
}

// ---------------- vocab MFMA pass 1: rsum8 only, m-split for occupancy ----------------
// grid (391, 2): y = m-half (rows y*64 .. y*64+63)
__global__ void k_vsum(const float* __restrict__ hid, const float* __restrict__ Wov,
                       const float* __restrict__ bov, float* __restrict__ rsum8) {
    __shared__ float sm[4][64];
    int L = threadIdx.x & 63, w = threadIdx.x >> 6;
    int lrow = L & 15, lk = L >> 4;
    int n0 = blockIdx.x * 128 + w * 32;
    int mb = blockIdx.y * 64;
    bf16x8 bfr[2][4];
    #pragma unroll
    for (int nt = 0; nt < 2; ++nt) {
        int n = n0 + nt * 16 + lrow;
        #pragma unroll
        for (int kk = 0; kk < 4; ++kk) {
            bf16x8 f;
            if (n < V_) {
                const float* p = Wov + (size_t)n * 128 + kk * 32 + lk * 8;
                float4 x = *(const float4*)p, y = *(const float4*)(p + 4);
                f[0]=f2bf(x.x); f[1]=f2bf(x.y); f[2]=f2bf(x.z); f[3]=f2bf(x.w);
                f[4]=f2bf(y.x); f[5]=f2bf(y.y); f[6]=f2bf(y.z); f[7]=f2bf(y.w);
            } else {
                #pragma unroll
                for (int j = 0; j < 8; ++j) f[j] = 0;
            }
            bfr[nt][kk] = f;
        }
    }
    f32x4 acc[4][2] = {};
    #pragma unroll
    for (int mt = 0; mt < 4; ++mt) {
        bf16x8 afr[4];
        #pragma unroll
        for (int kk = 0; kk < 4; ++kk) {
            const float* p = hid + (size_t)(mb + mt * 16 + lrow) * 128 + kk * 32 + lk * 8;
            float4 x = *(const float4*)p, y = *(const float4*)(p + 4);
            bf16x8 f;
            f[0]=f2bf(x.x); f[1]=f2bf(x.y); f[2]=f2bf(x.z); f[3]=f2bf(x.w);
            f[4]=f2bf(y.x); f[5]=f2bf(y.y); f[6]=f2bf(y.z); f[7]=f2bf(y.w);
            afr[kk] = f;
        }
        #pragma unroll
        for (int nt = 0; nt < 2; ++nt)
            #pragma unroll
            for (int kk = 0; kk < 4; ++kk)
                acc[mt][nt] = __builtin_amdgcn_mfma_f32_16x16x32_bf16(
                    afr[kk], bfr[nt][kk], acc[mt][nt], 0, 0, 0);
    }
    float bv[2];
    #pragma unroll
    for (int nt = 0; nt < 2; ++nt) {
        int n = n0 + nt * 16 + lrow;
        bv[nt] = (n < V_) ? bov[n] : 0.f;
    }
    float rs[4][4];
    #pragma unroll
    for (int mt = 0; mt < 4; ++mt) {
        #pragma unroll
        for (int r = 0; r < 4; ++r) rs[mt][r] = 0.f;
        #pragma unroll
        for (int nt = 0; nt < 2; ++nt) {
            int n = n0 + nt * 16 + lrow;
            if (n < V_) {
                #pragma unroll
                for (int r = 0; r < 4; ++r)
                    rs[mt][r] += __expf(acc[mt][nt][r] + bv[nt]);
            }
        }
    }
    #pragma unroll
    for (int o = 1; o < 16; o <<= 1)
        #pragma unroll
        for (int mt = 0; mt < 4; ++mt)
            #pragma unroll
            for (int r = 0; r < 4; ++r) rs[mt][r] += __shfl_xor(rs[mt][r], o);
    if (lrow == 0) {
        #pragma unroll
        for (int mt = 0; mt < 4; ++mt)
            #pragma unroll
            for (int r = 0; r < 4; ++r)
                sm[w][mt * 16 + lk * 4 + r] = rs[mt][r];
    }
    __syncthreads();
    if (threadIdx.x < 64) {
        float p = sm[0][threadIdx.x] + sm[1][threadIdx.x]
                + sm[2][threadIdx.x] + sm[3][threadIdx.x];
        atomicAdd(&rsum8[(blockIdx.x & 7) * 128 + mb + threadIdx.x], p);
    }
}

// ---------------- vocab MFMA pass 2: recompute, scale, write (+pad) ----------------
__global__ void k_vwrite(const float* __restrict__ hid, const float* __restrict__ Wov,
                         const float* __restrict__ bov, const float* __restrict__ pgen,
                         const float* __restrict__ rsum8, float* __restrict__ out) {
    __shared__ float scs[128];
    if (blockIdx.x == 391) {     // pad-zero group
        for (int i = threadIdx.x; i < B_ * (L_ / 4); i += 256) {
            int b = i >> 7, k = i & 127;
            ((float4*)(out + (size_t)b * VL_ + V_))[k] = make_float4(0.f,0.f,0.f,0.f);
        }
        return;
    }
    if (threadIdx.x < 128) {
        float s = 0.f;
        #pragma unroll
        for (int j = 0; j < 8; ++j) s += rsum8[j * 128 + threadIdx.x];
        scs[threadIdx.x] = pgen[threadIdx.x] / s;
    }
    __syncthreads();
    int L = threadIdx.x & 63, w = threadIdx.x >> 6;
    int lrow = L & 15, lk = L >> 4;
    int n0 = blockIdx.x * 128 + w * 32;
    bf16x8 bfr[2][4];
    #pragma unroll
    for (int nt = 0; nt < 2; ++nt) {
        int n = n0 + nt * 16 + lrow;
        #pragma unroll
        for (int kk = 0; kk < 4; ++kk) {
            bf16x8 f;
            if (n < V_) {
                const float* p = Wov + (size_t)n * 128 + kk * 32 + lk * 8;
                float4 x = *(const float4*)p, y = *(const float4*)(p + 4);
                f[0]=f2bf(x.x); f[1]=f2bf(x.y); f[2]=f2bf(x.z); f[3]=f2bf(x.w);
                f[4]=f2bf(y.x); f[5]=f2bf(y.y); f[6]=f2bf(y.z); f[7]=f2bf(y.w);
            } else {
                #pragma unroll
                for (int j = 0; j < 8; ++j) f[j] = 0;
            }
            bfr[nt][kk] = f;
        }
    }
    f32x4 acc[8][2] = {};
    #pragma unroll
    for (int mt = 0; mt < 8; ++mt) {
        bf16x8 afr[4];
        #pragma unroll
        for (int kk = 0; kk < 4; ++kk) {
            const float* p = hid + (size_t)(mt * 16 + lrow) * 128 + kk * 32 + lk * 8;
            float4 x = *(const float4*)p, y = *(const float4*)(p + 4);
            bf16x8 f;
            f[0]=f2bf(x.x); f[1]=f2bf(x.y); f[2]=f2bf(x.z); f[3]=f2bf(x.w);
            f[4]=f2bf(y.x); f[5]=f2bf(y.y); f[6]=f2bf(y.z); f[7]=f2bf(y.w);
            afr[kk] = f;
        }
        #pragma unroll
        for (int nt = 0; nt < 2; ++nt)
            #pragma unroll
            for (int kk = 0; kk < 4; ++kk)
                acc[mt][nt] = __builtin_amdgcn_mfma_f32_16x16x32_bf16(
                    afr[kk], bfr[nt][kk], acc[mt][nt], 0, 0, 0);
    }
    float bv[2];
    #pragma unroll
    for (int nt = 0; nt < 2; ++nt) {
        int n = n0 + nt * 16 + lrow;
        bv[nt] = (n < V_) ? bov[n] : 0.f;
    }
    #pragma unroll
    for (int mt = 0; mt < 8; ++mt) {
        #pragma unroll
        for (int nt = 0; nt < 2; ++nt) {
            int n = n0 + nt * 16 + lrow;
            if (n < V_) {
                #pragma unroll
                for (int r = 0; r < 4; ++r) {
                    int row = mt * 16 + lk * 4 + r;
                    out[(size_t)row * VL_ + n] =
                        __expf(acc[mt][nt][r] + bv[nt]) * scs[row];
                }
            }
        }
    }
}

// ---------------- scatter copy distribution ----------------
__global__ void k_scatter(float* __restrict__ out, const int* __restrict__ full_input,
                          const float* __restrict__ attn, const float* __restrict__ pgen) {
    int idx = blockIdx.x * blockDim.x + threadIdx.x;  // L*B = 65536
    int b = idx & 127;
    int tok = full_input[idx];
    atomicAdd(&out[(size_t)b * VL_ + tok], (1.f - pgen[b]) * attn[idx]);
}

extern "C" void kernel_launch(void* const* d_in, const int* in_sizes, int n_in,
                              void* d_out, int out_size, void* d_ws, size_t ws_size,
                              hipStream_t stream) {
    const int*   input_ids = (const int*)d_in[0];
    const float* hidden    = (const float*)d_in[1];
    const float* enc       = (const float*)d_in[2];
    const int*   full_in   = (const int*)d_in[3];
    const float* emb_tab   = (const float*)d_in[4];
    const float* W_ih      = (const float*)d_in[5];
    const float* W_hh      = (const float*)d_in[6];
    const float* b_ih      = (const float*)d_in[7];
    const float* b_hh      = (const float*)d_in[8];
    const float* W_ds      = (const float*)d_in[9];
    const float* b_ds      = (const float*)d_in[10];
    const float* w_h       = (const float*)d_in[11];
    const float* att_v     = (const float*)d_in[12];
    const float* W_oh      = (const float*)d_in[13];
    const float* b_oh      = (const float*)d_in[14];
    const float* W_ov      = (const float*)d_in[15];
    const float* b_ov      = (const float*)d_in[16];
    const float* W_ptr     = (const float*)d_in[17];
    const float* b_ptr     = (const float*)d_in[18];

    float* out = (float*)d_out;
    float* p_final = out;                                  // [B, VL]
    float* h_out   = out + (size_t)B_ * VL_;               // [B, H2]
    float* attn    = out + (size_t)B_ * VL_ + B_ * H2_;    // [L, B]

    float* ws = (float*)d_ws;
    float* gxp    = ws;             // 2 * 196608 = 393216
    float* ghp    = gxp + 393216;   // 4 * 196608 = 786432
    float* comb   = ghp + 786432;   // 131072
    float* dslp   = comb + 131072;  // 4 * 65536 = 262144
    float* scores = dslp + 262144;  // 65536
    float* ctxp   = scores + 65536; // 8 * 65536 = 524288
    float* hid    = ctxp + 524288;  // 16384
    float* pgen   = hid + 16384;    // 128
    float* rsum8  = pgen + 128;     // 1024

    // 1. gate GEMMs -> partial buffers
    k_gates<<<dim3(4,48,6), dim3(256), 0, stream>>>(input_ids, emb_tab, hidden,
                                                    W_ih, W_hh, gxp, ghp);
    // 2. GRU -> h_new; init hid=b_oh, rsum8=0
    k_gru<<<dim3(256), dim3(256), 0, stream>>>(gxp, ghp, b_ih, b_hh, hidden, b_oh,
                                               comb, h_out, hid, rsum8);
    // 3. dsl partials (split-K 4, plain stores)
    gemm_t<32,32,32,2,2,4,false><<<dim3(4,16,4), dim3(256), 0, stream>>>(
        comb, 2*H2_, W_ds, H2_, dslp, H2_, H2_, H2_, B_*H2_);
    // 4. attention scores
    k_scores<<<dim3(2048), dim3(256), 0, stream>>>(enc, dslp, b_ds, w_h, att_v, scores);
    // 5. FUSED softmax + context partials (+ attn write)
    k_sctx<<<dim3(B_, 8), dim3(128), 0, stream>>>(enc, scores, attn, ctxp);
    // 6. ctx reduce + p_gen
    k_ctxpgen<<<dim3(B_), dim3(128), 0, stream>>>(ctxp, input_ids, emb_tab,
                                                  W_ptr, b_ptr, comb, pgen);
    // 7. hid = comb @ W_oh^T + b_oh (split-K 8, atomic onto bias init)
    gemm_t<32,32,32,2,2,8,true><<<dim3(4,4,8), dim3(256), 0, stream>>>(
        comb, 2*H2_, W_oh, 2*H2_, hid, E_, E_, 2*H2_, 0);
    // 8. vocab pass 1: rsum8 (m-split for occupancy)
    k_vsum<<<dim3(391, 2), dim3(256), 0, stream>>>(hid, W_ov, b_ov, rsum8);
    // 9. vocab pass 2: recompute, scale, write p_final (+ zero pad)
    k_vwrite<<<dim3(392), dim3(256), 0, stream>>>(hid, W_ov, b_ov, pgen, rsum8, p_final);
    // 10. scatter
    k_scatter<<<dim3(L_*B_/256), dim3(256), 0, stream>>>(p_final, full_in, attn, pgen);
}

// Round 12
// 153.312 us; speedup vs baseline: 1.5257x; 1.0395x over previous
//
#include <hip/hip_runtime.h>
#include <math.h>

#define B_  128
#define E_  128
#define H2_ 512
#define H3_ 1536
#define L_  512
#define V_  50000
#define VL_ 50512   // V + L

typedef short bf16x8 __attribute__((ext_vector_type(8)));
typedef float f32x4 __attribute__((ext_vector_type(4)));

__device__ __forceinline__ float fast_tanh(float x) {
    float e = __expf(2.f * x);
    return 1.f - 2.f / (e + 1.f);
}
__device__ __forceinline__ float fast_sigmoid(float x) {
    return 1.f / (1.f + __expf(-x));
}
__device__ __forceinline__ short f2bf(float f) {
    unsigned u = __float_as_uint(f);
    u += 0x7fff + ((u >> 16) & 1);        // RNE
    return (short)(u >> 16);
}

// ---------------- gx & gh GEMMs, split-K -> PARTIAL buffers (no atomics) -------------
__global__ void k_gates(const int* __restrict__ ids, const float* __restrict__ tab,
                        const float* __restrict__ hidden,
                        const float* __restrict__ W_ih, const float* __restrict__ W_hh,
                        float* __restrict__ gxp, float* __restrict__ ghp) {
    __shared__ float As[32][36];
    __shared__ float Ws[32][36];
    int z = blockIdx.z;
    int which = (z < 2) ? 0 : 1;
    int kbeg  = which ? (z - 2) * 128 : z * 64;
    int kiter = which ? 4 : 2;
    const float* W = which ? W_hh : W_ih;
    int ldw = which ? H2_ : E_;
    float* C = which ? (ghp + (size_t)(z - 2) * B_ * H3_) : (gxp + (size_t)z * B_ * H3_);
    int bm = blockIdx.x * 32, bn = blockIdx.y * 32;
    int tid = threadIdx.x;
    int tm0 = (tid / 16) * 2, tn0 = (tid % 16) * 2;
    float acc[2][2] = {};
    for (int it = 0; it < kiter; ++it) {
        int k0 = kbeg + it * 32;
        for (int v = tid; v < 256; v += 256) {
            int m = v >> 3, q = (v & 7) << 2;
            int gm = bm + m;
            const float* arow = which ? (hidden + (size_t)gm * H2_)
                                      : (tab + (size_t)ids[gm] * E_);
            float4 x = *(const float4*)(arow + k0 + q);
            As[q+0][m] = x.x; As[q+1][m] = x.y; As[q+2][m] = x.z; As[q+3][m] = x.w;
        }
        for (int v = tid; v < 256; v += 256) {
            int n = v >> 3, q = (v & 7) << 2;
            float4 x = *(const float4*)(W + (size_t)(bn + n) * ldw + k0 + q);
            Ws[q+0][n] = x.x; Ws[q+1][n] = x.y; Ws[q+2][n] = x.z; Ws[q+3][n] = x.w;
        }
        __syncthreads();
        #pragma unroll
        for (int kk = 0; kk < 32; ++kk) {
            float a0 = As[kk][tm0], a1 = As[kk][tm0+1];
            float w0 = Ws[kk][tn0], w1 = Ws[kk][tn0+1];
            acc[0][0] += a0*w0; acc[0][1] += a0*w1;
            acc[1][0] += a1*w0; acc[1][1] += a1*w1;
        }
        __syncthreads();
    }
    #pragma unroll
    for (int i = 0; i < 2; ++i)
        #pragma unroll
        for (int j = 0; j < 2; ++j)
            C[(size_t)(bm+tm0+i) * H3_ + bn+tn0+j] = acc[i][j];
}

// ---------------- dsl GEMM: split-K 4 -> partial buffers ----------------
template<int BM, int BN, int BK, int TM, int TN, int SPLITK>
__global__ void gemm_part(const float* __restrict__ A, int lda,
                          const float* __restrict__ W, int ldw,
                          float* __restrict__ C, int ldc,
                          int N, int K, int partElems) {
    __shared__ float As[BK][BM + 4];
    __shared__ float Ws[BK][BN + 4];
    int bm = blockIdx.x * BM, bn = blockIdx.y * BN;
    int tid = threadIdx.x;
    constexpr int NT = BN / TN;
    int tm0 = (tid / NT) * TM;
    int tn0 = (tid % NT) * TN;
    int kchunk = K / SPLITK;
    int kbeg = blockIdx.z * kchunk;
    float acc[TM][TN] = {};
    for (int k0 = kbeg; k0 < kbeg + kchunk; k0 += BK) {
        #pragma unroll
        for (int v = tid; v < BM * BK / 4; v += 256) {
            int m = v / (BK / 4), q = (v % (BK / 4)) * 4;
            float4 x = *(const float4*)(A + (size_t)(bm + m) * lda + k0 + q);
            As[q+0][m] = x.x; As[q+1][m] = x.y; As[q+2][m] = x.z; As[q+3][m] = x.w;
        }
        #pragma unroll
        for (int v = tid; v < BN * BK / 4; v += 256) {
            int n = v / (BK / 4), q = (v % (BK / 4)) * 4;
            float4 x = *(const float4*)(W + (size_t)(bn + n) * ldw + k0 + q);
            Ws[q+0][n] = x.x; Ws[q+1][n] = x.y; Ws[q+2][n] = x.z; Ws[q+3][n] = x.w;
        }
        __syncthreads();
        #pragma unroll
        for (int kk = 0; kk < BK; ++kk) {
            float a[TM], w[TN];
            #pragma unroll
            for (int i = 0; i < TM; ++i) a[i] = As[kk][tm0 + i];
            #pragma unroll
            for (int j = 0; j < TN; ++j) w[j] = Ws[kk][tn0 + j];
            #pragma unroll
            for (int i = 0; i < TM; ++i)
                #pragma unroll
                for (int j = 0; j < TN; ++j) acc[i][j] += a[i] * w[j];
        }
        __syncthreads();
    }
    float* Cz = C + (size_t)blockIdx.z * partElems;
    #pragma unroll
    for (int i = 0; i < TM; ++i)
        #pragma unroll
        for (int j = 0; j < TN; ++j)
            Cz[(size_t)(bm+tm0+i) * ldc + bn+tn0+j] = acc[i][j];
}

// ---------------- GRU: reduce gate partials + biases; init rsum8 ----------------
__global__ void k_gru(const float* __restrict__ gxp, const float* __restrict__ ghp,
                      const float* __restrict__ b_ih, const float* __restrict__ b_hh,
                      const float* __restrict__ h0,
                      float* __restrict__ comb, float* __restrict__ hout,
                      float* __restrict__ rsum8) {
    int idx = blockIdx.x * blockDim.x + threadIdx.x;  // B*H2 = 65536
    int b = idx >> 9, h = idx & 511;
    const float* gx0 = gxp + (size_t)b * H3_;
    const float* gx1 = gx0 + (size_t)B_ * H3_;
    float xr = gx0[h]         + gx1[h]         + b_ih[h];
    float xz = gx0[H2_+h]     + gx1[H2_+h]     + b_ih[H2_+h];
    float xn = gx0[2*H2_+h]   + gx1[2*H2_+h]   + b_ih[2*H2_+h];
    float hr = b_hh[h], hz = b_hh[H2_+h], hn = b_hh[2*H2_+h];
    #pragma unroll
    for (int z = 0; z < 4; ++z) {
        const float* g = ghp + ((size_t)z * B_ + b) * H3_;
        hr += g[h]; hz += g[H2_+h]; hn += g[2*H2_+h];
    }
    float r = fast_sigmoid(xr + hr);
    float zz = fast_sigmoid(xz + hz);
    float n = fast_tanh(xn + r * hn);
    float hv = (1.f - zz) * n + zz * h0[idx];
    comb[b * (2 * H2_) + h] = hv;
    hout[idx] = hv;
    if (idx < 1024) rsum8[idx] = 0.f;
}

// ---------------- attention scores: one wave = 8 l's x same b; dsl from partials -----
__global__ void k_scores(const float* __restrict__ enc, const float* __restrict__ dslp,
                         const float* __restrict__ b_ds,
                         const float* __restrict__ w_h, const float* __restrict__ att_v,
                         float* __restrict__ scores) {
    int wid = (blockIdx.x << 2) + (threadIdx.x >> 6);  // 8192 waves
    int lane = threadIdx.x & 63;
    int b = wid & 127, lg = wid >> 7;                  // 64 l-groups of 8
    int l0 = lg << 3;
    const float4* w4 = (const float4*)w_h;
    const float4* v4 = (const float4*)att_v;
    const float4* bd4 = (const float4*)b_ds;
    float4 d0 = bd4[lane], d1 = bd4[lane + 64];
    #pragma unroll
    for (int z = 0; z < 4; ++z) {
        const float4* dp = (const float4*)(dslp + (size_t)z * B_ * H2_ + b * H2_);
        float4 p0 = dp[lane], p1 = dp[lane + 64];
        d0.x += p0.x; d0.y += p0.y; d0.z += p0.z; d0.w += p0.w;
        d1.x += p1.x; d1.y += p1.y; d1.z += p1.z; d1.w += p1.w;
    }
    float4 w0 = w4[lane], w1 = w4[lane + 64];
    float4 v0 = v4[lane], v1 = v4[lane + 64];
    float4 e0[8], e1[8];
    #pragma unroll
    for (int q = 0; q < 8; ++q) {
        const float4* e4 = (const float4*)(enc + ((size_t)((l0 + q) * B_ + b)) * H2_);
        e0[q] = e4[lane];
        e1[q] = e4[lane + 64];
    }
    float s[8];
    #pragma unroll
    for (int q = 0; q < 8; ++q) {
        float t;
        t  = v0.x * fast_tanh(w0.x * e0[q].x + d0.x);
        t += v0.y * fast_tanh(w0.y * e0[q].y + d0.y);
        t += v0.z * fast_tanh(w0.z * e0[q].z + d0.z);
        t += v0.w * fast_tanh(w0.w * e0[q].w + d0.w);
        t += v1.x * fast_tanh(w1.x * e1[q].x + d1.x);
        t += v1.y * fast_tanh(w1.y * e1[q].y + d1.y);
        t += v1.z * fast_tanh(w1.z * e1[q].z + d1.z);
        t += v1.w * fast_tanh(w1.w * e1[q].w + d1.w);
        s[q] = t;
    }
    #pragma unroll
    for (int q = 0; q < 8; ++q) {
        float t = s[q];
        #pragma unroll
        for (int o = 32; o; o >>= 1) t += __shfl_xor(t, o);
        if (lane == 0) scores[(l0 + q) * B_ + b] = t;
    }
}

// ---------------- softmax over batch axis (per l) ----------------
__global__ void k_softmax(const float* __restrict__ scores, float* __restrict__ attn) {
    int l = blockIdx.x, lane = threadIdx.x;   // 64 threads
    float s0 = scores[l * B_ + lane], s1 = scores[l * B_ + lane + 64];
    float m = fmaxf(s0, s1);
    #pragma unroll
    for (int o = 32; o; o >>= 1) m = fmaxf(m, __shfl_xor(m, o));
    float e0 = __expf(s0 - m), e1 = __expf(s1 - m);
    float t = e0 + e1;
    #pragma unroll
    for (int o = 32; o; o >>= 1) t += __shfl_xor(t, o);
    float inv = 1.f / t;
    attn[l * B_ + lane] = e0 * inv;
    attn[l * B_ + lane + 64] = e1 * inv;
}

// ---------------- context partials: block (b, l-chunk of 64), plain stores -----------
__global__ void k_context(const float* __restrict__ enc, const float* __restrict__ attn,
                          float* __restrict__ ctxp) {
    int b = blockIdx.x;
    int l0 = blockIdx.y << 6;
    int tid = threadIdx.x;               // 128 threads, float4 over h
    __shared__ float a_s[64];
    if (tid < 64) a_s[tid] = attn[(l0 + tid) * B_ + b];
    __syncthreads();
    const float4* e = (const float4*)(enc + ((size_t)l0 * B_ + b) * H2_) + tid;
    float4 c = make_float4(0.f, 0.f, 0.f, 0.f);
    #pragma unroll 8
    for (int i = 0; i < 64; ++i) {
        float4 x = e[(size_t)i * (B_ * H2_ / 4)];
        float a = a_s[i];
        c.x += a * x.x; c.y += a * x.y; c.z += a * x.z; c.w += a * x.w;
    }
    ((float4*)(ctxp + ((size_t)blockIdx.y * B_ + b) * H2_))[tid] = c;
}

// ---------------- ctx reduce + p_gen + hid mini-GEMM: 128 blocks x 128 thr -----------
__global__ void k_cph(const float* __restrict__ ctxp, const int* __restrict__ ids,
                      const float* __restrict__ tab, const float* __restrict__ W_ptr,
                      const float* __restrict__ b_ptr, const float* __restrict__ W_oh,
                      const float* __restrict__ b_oh,
                      float* __restrict__ comb, float* __restrict__ pgen,
                      float* __restrict__ hid) {
    __shared__ float cmb[1024];
    __shared__ float red[128];
    int b = blockIdx.x, tid = threadIdx.x;   // tid = h4 slot / n index
    float4 c = make_float4(0.f, 0.f, 0.f, 0.f);
    #pragma unroll
    for (int z = 0; z < 8; ++z) {
        float4 x = ((const float4*)(ctxp + ((size_t)z * B_ + b) * H2_))[tid];
        c.x += x.x; c.y += x.y; c.z += x.z; c.w += x.w;
    }
    ((float4*)(comb + b * (2 * H2_) + H2_))[tid] = c;
    ((float4*)(cmb + H2_))[tid] = c;
    float4 hn = ((const float4*)(comb + b * (2 * H2_)))[tid];
    ((float4*)cmb)[tid] = hn;
    // p_gen dot
    const float4* wp = (const float4*)W_ptr;
    float4 wh = wp[tid], wc = wp[128 + tid];
    float s = hn.x*wh.x + hn.y*wh.y + hn.z*wh.z + hn.w*wh.w
            + c.x*wc.x + c.y*wc.y + c.z*wc.z + c.w*wc.w;
    if (tid < 32) {
        float4 ev = ((const float4*)(tab + (size_t)ids[b] * E_))[tid];
        float4 we = wp[256 + tid];
        s += ev.x*we.x + ev.y*we.y + ev.z*we.z + ev.w*we.w;
    }
    red[tid] = s;
    __syncthreads();
    if (tid < 64) {
        float tt = red[tid] + red[tid + 64];
        #pragma unroll
        for (int o = 32; o; o >>= 1) tt += __shfl_xor(tt, o);
        if (tid == 0) pgen[b] = fast_sigmoid(tt + b_ptr[0]);
    }
    // hid[b][n]: n = tid, dot over 1024 (cmb LDS broadcast, W_oh row stream from L2)
    float acc = b_oh[tid];
    const float4* wr = (const float4*)(W_oh + (size_t)tid * (2 * H2_));
    #pragma unroll 8
    for (int k = 0; k < 256; ++k) {
        float4 ww = wr[k];
        acc += cmb[k*4+0]*ww.x + cmb[k*4+1]*ww.y + cmb[k*4+2]*ww.z + cmb[k*4+3]*ww.w;
    }
    hid[b * E_ + tid] = acc;
}

// ---------------- vocab MFMA pass 1: rsum8 only ----------------
__global__ void k_vsum(const float* __restrict__ hid, const float* __restrict__ Wov,
                       const float* __restrict__ bov, float* __restrict__ rsum8) {
    __shared__ float sm[4][128];
    int L = threadIdx.x & 63, w = threadIdx.x >> 6;
    int lrow = L & 15, lk = L >> 4;
    int n0 = blockIdx.x * 128 + w * 32;
    bf16x8 bfr[2][4];
    #pragma unroll
    for (int nt = 0; nt < 2; ++nt) {
        int n = n0 + nt * 16 + lrow;
        #pragma unroll
        for (int kk = 0; kk < 4; ++kk) {
            bf16x8 f;
            if (n < V_) {
                const float* p = Wov + (size_t)n * 128 + kk * 32 + lk * 8;
                float4 x = *(const float4*)p, y = *(const float4*)(p + 4);
                f[0]=f2bf(x.x); f[1]=f2bf(x.y); f[2]=f2bf(x.z); f[3]=f2bf(x.w);
                f[4]=f2bf(y.x); f[5]=f2bf(y.y); f[6]=f2bf(y.z); f[7]=f2bf(y.w);
            } else {
                #pragma unroll
                for (int j = 0; j < 8; ++j) f[j] = 0;
            }
            bfr[nt][kk] = f;
        }
    }
    f32x4 acc[8][2] = {};
    #pragma unroll
    for (int mt = 0; mt < 8; ++mt) {
        bf16x8 afr[4];
        #pragma unroll
        for (int kk = 0; kk < 4; ++kk) {
            const float* p = hid + (size_t)(mt * 16 + lrow) * 128 + kk * 32 + lk * 8;
            float4 x = *(const float4*)p, y = *(const float4*)(p + 4);
            bf16x8 f;
            f[0]=f2bf(x.x); f[1]=f2bf(x.y); f[2]=f2bf(x.z); f[3]=f2bf(x.w);
            f[4]=f2bf(y.x); f[5]=f2bf(y.y); f[6]=f2bf(y.z); f[7]=f2bf(y.w);
            afr[kk] = f;
        }
        #pragma unroll
        for (int nt = 0; nt < 2; ++nt)
            #pragma unroll
            for (int kk = 0; kk < 4; ++kk)
                acc[mt][nt] = __builtin_amdgcn_mfma_f32_16x16x32_bf16(
                    afr[kk], bfr[nt][kk], acc[mt][nt], 0, 0, 0);
    }
    float bv[2];
    #pragma unroll
    for (int nt = 0; nt < 2; ++nt) {
        int n = n0 + nt * 16 + lrow;
        bv[nt] = (n < V_) ? bov[n] : 0.f;
    }
    float rs[8][4];
    #pragma unroll
    for (int mt = 0; mt < 8; ++mt) {
        #pragma unroll
        for (int r = 0; r < 4; ++r) rs[mt][r] = 0.f;
        #pragma unroll
        for (int nt = 0; nt < 2; ++nt) {
            int n = n0 + nt * 16 + lrow;
            if (n < V_) {
                #pragma unroll
                for (int r = 0; r < 4; ++r)
                    rs[mt][r] += __expf(acc[mt][nt][r] + bv[nt]);
            }
        }
    }
    #pragma unroll
    for (int o = 1; o < 16; o <<= 1)
        #pragma unroll
        for (int mt = 0; mt < 8; ++mt)
            #pragma unroll
            for (int r = 0; r < 4; ++r) rs[mt][r] += __shfl_xor(rs[mt][r], o);
    if (lrow == 0) {
        #pragma unroll
        for (int mt = 0; mt < 8; ++mt)
            #pragma unroll
            for (int r = 0; r < 4; ++r)
                sm[w][mt * 16 + lk * 4 + r] = rs[mt][r];
    }
    __syncthreads();
    if (threadIdx.x < 128) {
        float p = sm[0][threadIdx.x] + sm[1][threadIdx.x]
                + sm[2][threadIdx.x] + sm[3][threadIdx.x];
        atomicAdd(&rsum8[(blockIdx.x & 7) * 128 + threadIdx.x], p);
    }
}

// ---------------- vocab MFMA pass 2: recompute, scale, write (+pad) ----------------
__global__ void k_vwrite(const float* __restrict__ hid, const float* __restrict__ Wov,
                         const float* __restrict__ bov, const float* __restrict__ pgen,
                         const float* __restrict__ rsum8, float* __restrict__ out) {
    __shared__ float scs[128];
    if (blockIdx.x == 391) {     // pad-zero group
        for (int i = threadIdx.x; i < B_ * (L_ / 4); i += 256) {
            int b = i >> 7, k = i & 127;
            ((float4*)(out + (size_t)b * VL_ + V_))[k] = make_float4(0.f,0.f,0.f,0.f);
        }
        return;
    }
    if (threadIdx.x < 128) {
        float s = 0.f;
        #pragma unroll
        for (int j = 0; j < 8; ++j) s += rsum8[j * 128 + threadIdx.x];
        scs[threadIdx.x] = pgen[threadIdx.x] / s;
    }
    __syncthreads();
    int L = threadIdx.x & 63, w = threadIdx.x >> 6;
    int lrow = L & 15, lk = L >> 4;
    int n0 = blockIdx.x * 128 + w * 32;
    bf16x8 bfr[2][4];
    #pragma unroll
    for (int nt = 0; nt < 2; ++nt) {
        int n = n0 + nt * 16 + lrow;
        #pragma unroll
        for (int kk = 0; kk < 4; ++kk) {
            bf16x8 f;
            if (n < V_) {
                const float* p = Wov + (size_t)n * 128 + kk * 32 + lk * 8;
                float4 x = *(const float4*)p, y = *(const float4*)(p + 4);
                f[0]=f2bf(x.x); f[1]=f2bf(x.y); f[2]=f2bf(x.z); f[3]=f2bf(x.w);
                f[4]=f2bf(y.x); f[5]=f2bf(y.y); f[6]=f2bf(y.z); f[7]=f2bf(y.w);
            } else {
                #pragma unroll
                for (int j = 0; j < 8; ++j) f[j] = 0;
            }
            bfr[nt][kk] = f;
        }
    }
    f32x4 acc[8][2] = {};
    #pragma unroll
    for (int mt = 0; mt < 8; ++mt) {
        bf16x8 afr[4];
        #pragma unroll
        for (int kk = 0; kk < 4; ++kk) {
            const float* p = hid + (size_t)(mt * 16 + lrow) * 128 + kk * 32 + lk * 8;
            float4 x = *(const float4*)p, y = *(const float4*)(p + 4);
            bf16x8 f;
            f[0]=f2bf(x.x); f[1]=f2bf(x.y); f[2]=f2bf(x.z); f[3]=f2bf(x.w);
            f[4]=f2bf(y.x); f[5]=f2bf(y.y); f[6]=f2bf(y.z); f[7]=f2bf(y.w);
            afr[kk] = f;
        }
        #pragma unroll
        for (int nt = 0; nt < 2; ++nt)
            #pragma unroll
            for (int kk = 0; kk < 4; ++kk)
                acc[mt][nt] = __builtin_amdgcn_mfma_f32_16x16x32_bf16(
                    afr[kk], bfr[nt][kk], acc[mt][nt], 0, 0, 0);
    }
    float bv[2];
    #pragma unroll
    for (int nt = 0; nt < 2; ++nt) {
        int n = n0 + nt * 16 + lrow;
        bv[nt] = (n < V_) ? bov[n] : 0.f;
    }
    #pragma unroll
    for (int mt = 0; mt < 8; ++mt) {
        #pragma unroll
        for (int nt = 0; nt < 2; ++nt) {
            int n = n0 + nt * 16 + lrow;
            if (n < V_) {
                #pragma unroll
                for (int r = 0; r < 4; ++r) {
                    int row = mt * 16 + lk * 4 + r;
                    out[(size_t)row * VL_ + n] =
                        __expf(acc[mt][nt][r] + bv[nt]) * scs[row];
                }
            }
        }
    }
}

// ---------------- scatter copy distribution ----------------
__global__ void k_scatter(float* __restrict__ out, const int* __restrict__ full_input,
                          const float* __restrict__ attn, const float* __restrict__ pgen) {
    int idx = blockIdx.x * blockDim.x + threadIdx.x;  // L*B = 65536
    int b = idx & 127;
    int tok = full_input[idx];
    atomicAdd(&out[(size_t)b * VL_ + tok], (1.f - pgen[b]) * attn[idx]);
}

extern "C" void kernel_launch(void* const* d_in, const int* in_sizes, int n_in,
                              void* d_out, int out_size, void* d_ws, size_t ws_size,
                              hipStream_t stream) {
    const int*   input_ids = (const int*)d_in[0];
    const float* hidden    = (const float*)d_in[1];
    const float* enc       = (const float*)d_in[2];
    const int*   full_in   = (const int*)d_in[3];
    const float* emb_tab   = (const float*)d_in[4];
    const float* W_ih      = (const float*)d_in[5];
    const float* W_hh      = (const float*)d_in[6];
    const float* b_ih      = (const float*)d_in[7];
    const float* b_hh      = (const float*)d_in[8];
    const float* W_ds      = (const float*)d_in[9];
    const float* b_ds      = (const float*)d_in[10];
    const float* w_h       = (const float*)d_in[11];
    const float* att_v     = (const float*)d_in[12];
    const float* W_oh      = (const float*)d_in[13];
    const float* b_oh      = (const float*)d_in[14];
    const float* W_ov      = (const float*)d_in[15];
    const float* b_ov      = (const float*)d_in[16];
    const float* W_ptr     = (const float*)d_in[17];
    const float* b_ptr     = (const float*)d_in[18];

    float* out = (float*)d_out;
    float* p_final = out;                                  // [B, VL]
    float* h_out   = out + (size_t)B_ * VL_;               // [B, H2]
    float* attn    = out + (size_t)B_ * VL_ + B_ * H2_;    // [L, B]

    float* ws = (float*)d_ws;
    float* gxp    = ws;             // 2 * 196608 = 393216
    float* ghp    = gxp + 393216;   // 4 * 196608 = 786432
    float* comb   = ghp + 786432;   // 131072
    float* dslp   = comb + 131072;  // 4 * 65536 = 262144
    float* scores = dslp + 262144;  // 65536
    float* ctxp   = scores + 65536; // 8 * 65536 = 524288
    float* hid    = ctxp + 524288;  // 16384
    float* pgen   = hid + 16384;    // 128
    float* rsum8  = pgen + 128;     // 1024

    // 1. gate GEMMs -> partial buffers
    k_gates<<<dim3(4,48,6), dim3(256), 0, stream>>>(input_ids, emb_tab, hidden,
                                                    W_ih, W_hh, gxp, ghp);
    // 2. GRU -> h_new; rsum8 = 0
    k_gru<<<dim3(256), dim3(256), 0, stream>>>(gxp, ghp, b_ih, b_hh, hidden,
                                               comb, h_out, rsum8);
    // 3. dsl partials (split-K 4, plain stores)
    gemm_part<32,32,32,2,2,4><<<dim3(4,16,4), dim3(256), 0, stream>>>(
        comb, 2*H2_, W_ds, H2_, dslp, H2_, H2_, H2_, B_*H2_);
    // 4. attention scores (8 l's per wave; dsl summed from partials + b_ds)
    k_scores<<<dim3(2048), dim3(256), 0, stream>>>(enc, dslp, b_ds, w_h, att_v, scores);
    // 5. softmax over batch axis
    k_softmax<<<dim3(L_), dim3(64), 0, stream>>>(scores, attn);
    // 6. context partials (plain stores)
    k_context<<<dim3(B_, 8), dim3(128), 0, stream>>>(enc, attn, ctxp);
    // 7. ctx reduce + p_gen + hid (fused)
    k_cph<<<dim3(B_), dim3(128), 0, stream>>>(ctxp, input_ids, emb_tab, W_ptr, b_ptr,
                                              W_oh, b_oh, comb, pgen, hid);
    // 8. vocab pass 1: rsum8 partials only
    k_vsum<<<dim3(391), dim3(256), 0, stream>>>(hid, W_ov, b_ov, rsum8);
    // 9. vocab pass 2: recompute, scale, write p_final (+ zero pad)
    k_vwrite<<<dim3(392), dim3(256), 0, stream>>>(hid, W_ov, b_ov, pgen, rsum8, p_final);
    // 10. scatter
    k_scatter<<<dim3(L_*B_/256), dim3(256), 0, stream>>>(p_final, full_in, attn, pgen);
}

// Round 13
// 140.812 us; speedup vs baseline: 1.6611x; 1.0888x over previous
//
#include <hip/hip_runtime.h>
#include <math.h>

#define B_  128
#define E_  128
#define H2_ 512
#define H3_ 1536
#define L_  512
#define V_  50000
#define VL_ 50512   // V + L

typedef short bf16x8 __attribute__((ext_vector_type(8)));
typedef float f32x4 __attribute__((ext_vector_type(4)));

__device__ __forceinline__ float fast_tanh(float x) {
    float e = __expf(2.f * x);
    return 1.f - 2.f / (e + 1.f);
}
__device__ __forceinline__ float fast_sigmoid(float x) {
    return 1.f / (1.f + __expf(-x));
}
__device__ __forceinline__ short f2bf(float f) {
    unsigned u = __float_as_uint(f);
    u += 0x7fff + ((u >> 16) & 1);        // RNE
    return (short)(u >> 16);
}

// ---------------- gx & gh GEMMs, split-K -> PARTIAL buffers (no atomics) -------------
// z: 0-1 -> gxp[z] (K=128 halves), 2-5 -> ghp[z-2] (K=512 quarters)
__global__ void k_gates(const int* __restrict__ ids, const float* __restrict__ tab,
                        const float* __restrict__ hidden,
                        const float* __restrict__ W_ih, const float* __restrict__ W_hh,
                        float* __restrict__ gxp, float* __restrict__ ghp) {
    __shared__ float As[32][36];
    __shared__ float Ws[32][36];
    int z = blockIdx.z;
    int which = (z < 2) ? 0 : 1;
    int kbeg  = which ? (z - 2) * 128 : z * 64;
    int kiter = which ? 4 : 2;
    const float* W = which ? W_hh : W_ih;
    int ldw = which ? H2_ : E_;
    float* C = which ? (ghp + (size_t)(z - 2) * B_ * H3_) : (gxp + (size_t)z * B_ * H3_);
    int bm = blockIdx.x * 32, bn = blockIdx.y * 32;
    int tid = threadIdx.x;
    int tm0 = (tid / 16) * 2, tn0 = (tid % 16) * 2;
    float acc[2][2] = {};
    for (int it = 0; it < kiter; ++it) {
        int k0 = kbeg + it * 32;
        for (int v = tid; v < 256; v += 256) {
            int m = v >> 3, q = (v & 7) << 2;
            int gm = bm + m;
            const float* arow = which ? (hidden + (size_t)gm * H2_)
                                      : (tab + (size_t)ids[gm] * E_);
            float4 x = *(const float4*)(arow + k0 + q);
            As[q+0][m] = x.x; As[q+1][m] = x.y; As[q+2][m] = x.z; As[q+3][m] = x.w;
        }
        for (int v = tid; v < 256; v += 256) {
            int n = v >> 3, q = (v & 7) << 2;
            float4 x = *(const float4*)(W + (size_t)(bn + n) * ldw + k0 + q);
            Ws[q+0][n] = x.x; Ws[q+1][n] = x.y; Ws[q+2][n] = x.z; Ws[q+3][n] = x.w;
        }
        __syncthreads();
        #pragma unroll
        for (int kk = 0; kk < 32; ++kk) {
            float a0 = As[kk][tm0], a1 = As[kk][tm0+1];
            float w0 = Ws[kk][tn0], w1 = Ws[kk][tn0+1];
            acc[0][0] += a0*w0; acc[0][1] += a0*w1;
            acc[1][0] += a1*w0; acc[1][1] += a1*w1;
        }
        __syncthreads();
    }
    #pragma unroll
    for (int i = 0; i < 2; ++i)
        #pragma unroll
        for (int j = 0; j < 2; ++j)
            C[(size_t)(bm+tm0+i) * H3_ + bn+tn0+j] = acc[i][j];
}

// ---------------- generic tiled GEMM, split-K: partial-store or atomic ----------------
template<int BM, int BN, int BK, int TM, int TN, int SPLITK, bool ATOMIC>
__global__ void gemm_t(const float* __restrict__ A, int lda,
                       const float* __restrict__ W, int ldw,
                       float* __restrict__ C, int ldc,
                       int N, int K, int partElems) {
    __shared__ float As[BK][BM + 4];
    __shared__ float Ws[BK][BN + 4];
    int bm = blockIdx.x * BM, bn = blockIdx.y * BN;
    int tid = threadIdx.x;
    constexpr int NT = BN / TN;
    int tm0 = (tid / NT) * TM;
    int tn0 = (tid % NT) * TN;
    int kchunk = K / SPLITK;
    int kbeg = blockIdx.z * kchunk;
    float acc[TM][TN] = {};
    for (int k0 = kbeg; k0 < kbeg + kchunk; k0 += BK) {
        #pragma unroll
        for (int v = tid; v < BM * BK / 4; v += 256) {
            int m = v / (BK / 4), q = (v % (BK / 4)) * 4;
            float4 x = *(const float4*)(A + (size_t)(bm + m) * lda + k0 + q);
            As[q+0][m] = x.x; As[q+1][m] = x.y; As[q+2][m] = x.z; As[q+3][m] = x.w;
        }
        #pragma unroll
        for (int v = tid; v < BN * BK / 4; v += 256) {
            int n = v / (BK / 4), q = (v % (BK / 4)) * 4;
            float4 x = *(const float4*)(W + (size_t)(bn + n) * ldw + k0 + q);
            Ws[q+0][n] = x.x; Ws[q+1][n] = x.y; Ws[q+2][n] = x.z; Ws[q+3][n] = x.w;
        }
        __syncthreads();
        #pragma unroll
        for (int kk = 0; kk < BK; ++kk) {
            float a[TM], w[TN];
            #pragma unroll
            for (int i = 0; i < TM; ++i) a[i] = As[kk][tm0 + i];
            #pragma unroll
            for (int j = 0; j < TN; ++j) w[j] = Ws[kk][tn0 + j];
            #pragma unroll
            for (int i = 0; i < TM; ++i)
                #pragma unroll
                for (int j = 0; j < TN; ++j) acc[i][j] += a[i] * w[j];
        }
        __syncthreads();
    }
    float* Cz = ATOMIC ? C : (C + (size_t)blockIdx.z * partElems);
    #pragma unroll
    for (int i = 0; i < TM; ++i)
        #pragma unroll
        for (int j = 0; j < TN; ++j) {
            if (ATOMIC) atomicAdd(&Cz[(size_t)(bm+tm0+i) * ldc + bn+tn0+j], acc[i][j]);
            else        Cz[(size_t)(bm+tm0+i) * ldc + bn+tn0+j] = acc[i][j];
        }
}

// ---------------- GRU: reduce gate partials + biases; init hid/rsum8 ----------------
__global__ void k_gru(const float* __restrict__ gxp, const float* __restrict__ ghp,
                      const float* __restrict__ b_ih, const float* __restrict__ b_hh,
                      const float* __restrict__ h0, const float* __restrict__ b_oh,
                      float* __restrict__ comb, float* __restrict__ hout,
                      float* __restrict__ hid, float* __restrict__ rsum8) {
    int idx = blockIdx.x * blockDim.x + threadIdx.x;  // B*H2 = 65536
    int b = idx >> 9, h = idx & 511;
    const float* gx0 = gxp + (size_t)b * H3_;
    const float* gx1 = gx0 + (size_t)B_ * H3_;
    float xr = gx0[h]         + gx1[h]         + b_ih[h];
    float xz = gx0[H2_+h]     + gx1[H2_+h]     + b_ih[H2_+h];
    float xn = gx0[2*H2_+h]   + gx1[2*H2_+h]   + b_ih[2*H2_+h];
    float hr = b_hh[h], hz = b_hh[H2_+h], hn = b_hh[2*H2_+h];
    #pragma unroll
    for (int z = 0; z < 4; ++z) {
        const float* g = ghp + ((size_t)z * B_ + b) * H3_;
        hr += g[h]; hz += g[H2_+h]; hn += g[2*H2_+h];
    }
    float r = fast_sigmoid(xr + hr);
    float zz = fast_sigmoid(xz + hz);
    float n = fast_tanh(xn + r * hn);
    float hv = (1.f - zz) * n + zz * h0[idx];
    comb[b * (2 * H2_) + h] = hv;
    hout[idx] = hv;
    if (idx < B_ * E_) hid[idx] = b_oh[idx & 127];   // split-K atomic target init
    if (idx < 1024)    rsum8[idx] = 0.f;
}

// ---------------- attention scores: one wave = 8 l's x same b; dsl from partials -----
__global__ void k_scores(const float* __restrict__ enc, const float* __restrict__ dslp,
                         const float* __restrict__ b_ds,
                         const float* __restrict__ w_h, const float* __restrict__ att_v,
                         float* __restrict__ scores) {
    int wid = (blockIdx.x << 2) + (threadIdx.x >> 6);  // 8192 waves
    int lane = threadIdx.x & 63;
    int b = wid & 127, lg = wid >> 7;                  // 64 l-groups of 8
    int l0 = lg << 3;
    const float4* w4 = (const float4*)w_h;
    const float4* v4 = (const float4*)att_v;
    const float4* bd4 = (const float4*)b_ds;
    float4 d0 = bd4[lane], d1 = bd4[lane + 64];
    #pragma unroll
    for (int z = 0; z < 4; ++z) {
        const float4* dp = (const float4*)(dslp + (size_t)z * B_ * H2_ + b * H2_);
        float4 p0 = dp[lane], p1 = dp[lane + 64];
        d0.x += p0.x; d0.y += p0.y; d0.z += p0.z; d0.w += p0.w;
        d1.x += p1.x; d1.y += p1.y; d1.z += p1.z; d1.w += p1.w;
    }
    float4 w0 = w4[lane], w1 = w4[lane + 64];
    float4 v0 = v4[lane], v1 = v4[lane + 64];
    float4 e0[8], e1[8];
    #pragma unroll
    for (int q = 0; q < 8; ++q) {
        const float4* e4 = (const float4*)(enc + ((size_t)((l0 + q) * B_ + b)) * H2_);
        e0[q] = e4[lane];
        e1[q] = e4[lane + 64];
    }
    float s[8];
    #pragma unroll
    for (int q = 0; q < 8; ++q) {
        float t;
        t  = v0.x * fast_tanh(w0.x * e0[q].x + d0.x);
        t += v0.y * fast_tanh(w0.y * e0[q].y + d0.y);
        t += v0.z * fast_tanh(w0.z * e0[q].z + d0.z);
        t += v0.w * fast_tanh(w0.w * e0[q].w + d0.w);
        t += v1.x * fast_tanh(w1.x * e1[q].x + d1.x);
        t += v1.y * fast_tanh(w1.y * e1[q].y + d1.y);
        t += v1.z * fast_tanh(w1.z * e1[q].z + d1.z);
        t += v1.w * fast_tanh(w1.w * e1[q].w + d1.w);
        s[q] = t;
    }
    #pragma unroll
    for (int q = 0; q < 8; ++q) {
        float t = s[q];
        #pragma unroll
        for (int o = 32; o; o >>= 1) t += __shfl_xor(t, o);
        if (lane == 0) scores[(l0 + q) * B_ + b] = t;
    }
}

// ---------------- softmax over batch axis (per l) ----------------
__global__ void k_softmax(const float* __restrict__ scores, float* __restrict__ attn) {
    int l = blockIdx.x, lane = threadIdx.x;   // 64 threads
    float s0 = scores[l * B_ + lane], s1 = scores[l * B_ + lane + 64];
    float m = fmaxf(s0, s1);
    #pragma unroll
    for (int o = 32; o; o >>= 1) m = fmaxf(m, __shfl_xor(m, o));
    float e0 = __expf(s0 - m), e1 = __expf(s1 - m);
    float t = e0 + e1;
    #pragma unroll
    for (int o = 32; o; o >>= 1) t += __shfl_xor(t, o);
    float inv = 1.f / t;
    attn[l * B_ + lane] = e0 * inv;
    attn[l * B_ + lane + 64] = e1 * inv;
}

// ---------------- context partials: block (b, l-chunk of 64), plain stores -----------
__global__ void k_context(const float* __restrict__ enc, const float* __restrict__ attn,
                          float* __restrict__ ctxp) {
    int b = blockIdx.x;
    int l0 = blockIdx.y << 6;
    int tid = threadIdx.x;               // 128 threads, float4 over h
    __shared__ float a_s[64];
    if (tid < 64) a_s[tid] = attn[(l0 + tid) * B_ + b];
    __syncthreads();
    const float4* e = (const float4*)(enc + ((size_t)l0 * B_ + b) * H2_) + tid;
    float4 c = make_float4(0.f, 0.f, 0.f, 0.f);
    #pragma unroll 8
    for (int i = 0; i < 64; ++i) {
        float4 x = e[(size_t)i * (B_ * H2_ / 4)];
        float a = a_s[i];
        c.x += a * x.x; c.y += a * x.y; c.z += a * x.z; c.w += a * x.w;
    }
    ((float4*)(ctxp + ((size_t)blockIdx.y * B_ + b) * H2_))[tid] = c;
}

// ---------------- ctx reduce + p_gen: 128 blocks x 128 thr ----------------
__global__ void k_ctxpgen(const float* __restrict__ ctxp, const int* __restrict__ ids,
                          const float* __restrict__ tab, const float* __restrict__ W_ptr,
                          const float* __restrict__ b_ptr,
                          float* __restrict__ comb, float* __restrict__ pgen) {
    __shared__ float red[128];
    int b = blockIdx.x, tid = threadIdx.x;   // h4 = tid
    float4 c = make_float4(0.f, 0.f, 0.f, 0.f);
    #pragma unroll
    for (int z = 0; z < 8; ++z) {
        float4 x = ((const float4*)(ctxp + ((size_t)z * B_ + b) * H2_))[tid];
        c.x += x.x; c.y += x.y; c.z += x.z; c.w += x.w;
    }
    ((float4*)(comb + b * (2 * H2_) + H2_))[tid] = c;
    const float4* wp = (const float4*)W_ptr;
    float4 wc = wp[128 + tid];
    float s = c.x * wc.x + c.y * wc.y + c.z * wc.z + c.w * wc.w;
    float4 hv = ((const float4*)(comb + b * (2 * H2_)))[tid];
    float4 wh = wp[tid];
    s += hv.x * wh.x + hv.y * wh.y + hv.z * wh.z + hv.w * wh.w;
    if (tid < 32) {
        float4 ev = ((const float4*)(tab + (size_t)ids[b] * E_))[tid];
        float4 we = wp[256 + tid];
        s += ev.x * we.x + ev.y * we.y + ev.z * we.z + ev.w * we.w;
    }
    red[tid] = s;
    __syncthreads();
    if (tid < 64) {
        float t = red[tid] + red[tid + 64];
        #pragma unroll
        for (int o = 32; o; o >>= 1) t += __shfl_xor(t, o);
        if (tid == 0) pgen[b] = fast_sigmoid(t + b_ptr[0]);
    }
}

// ---------------- vocab MFMA pass 1: rsum8 only (no stores of exp) ----------------
__global__ void k_vsum(const float* __restrict__ hid, const float* __restrict__ Wov,
                       const float* __restrict__ bov, float* __restrict__ rsum8) {
    __shared__ float sm[4][128];
    int L = threadIdx.x & 63, w = threadIdx.x >> 6;
    int lrow = L & 15, lk = L >> 4;
    int n0 = blockIdx.x * 128 + w * 32;

    bf16x8 bfr[2][4];
    #pragma unroll
    for (int nt = 0; nt < 2; ++nt) {
        int n = n0 + nt * 16 + lrow;
        #pragma unroll
        for (int kk = 0; kk < 4; ++kk) {
            bf16x8 f;
            if (n < V_) {
                const float* p = Wov + (size_t)n * 128 + kk * 32 + lk * 8;
                float4 x = *(const float4*)p, y = *(const float4*)(p + 4);
                f[0]=f2bf(x.x); f[1]=f2bf(x.y); f[2]=f2bf(x.z); f[3]=f2bf(x.w);
                f[4]=f2bf(y.x); f[5]=f2bf(y.y); f[6]=f2bf(y.z); f[7]=f2bf(y.w);
            } else {
                #pragma unroll
                for (int j = 0; j < 8; ++j) f[j] = 0;
            }
            bfr[nt][kk] = f;
        }
    }
    f32x4 acc[8][2] = {};
    #pragma unroll
    for (int mt = 0; mt < 8; ++mt) {
        bf16x8 afr[4];
        #pragma unroll
        for (int kk = 0; kk < 4; ++kk) {
            const float* p = hid + (size_t)(mt * 16 + lrow) * 128 + kk * 32 + lk * 8;
            float4 x = *(const float4*)p, y = *(const float4*)(p + 4);
            bf16x8 f;
            f[0]=f2bf(x.x); f[1]=f2bf(x.y); f[2]=f2bf(x.z); f[3]=f2bf(x.w);
            f[4]=f2bf(y.x); f[5]=f2bf(y.y); f[6]=f2bf(y.z); f[7]=f2bf(y.w);
            afr[kk] = f;
        }
        #pragma unroll
        for (int nt = 0; nt < 2; ++nt)
            #pragma unroll
            for (int kk = 0; kk < 4; ++kk)
                acc[mt][nt] = __builtin_amdgcn_mfma_f32_16x16x32_bf16(
                    afr[kk], bfr[nt][kk], acc[mt][nt], 0, 0, 0);
    }
    float bv[2];
    #pragma unroll
    for (int nt = 0; nt < 2; ++nt) {
        int n = n0 + nt * 16 + lrow;
        bv[nt] = (n < V_) ? bov[n] : 0.f;
    }
    float rs[8][4];
    #pragma unroll
    for (int mt = 0; mt < 8; ++mt) {
        #pragma unroll
        for (int r = 0; r < 4; ++r) rs[mt][r] = 0.f;
        #pragma unroll
        for (int nt = 0; nt < 2; ++nt) {
            int n = n0 + nt * 16 + lrow;
            if (n < V_) {
                #pragma unroll
                for (int r = 0; r < 4; ++r)
                    rs[mt][r] += __expf(acc[mt][nt][r] + bv[nt]);
            }
        }
    }
    #pragma unroll
    for (int o = 1; o < 16; o <<= 1)
        #pragma unroll
        for (int mt = 0; mt < 8; ++mt)
            #pragma unroll
            for (int r = 0; r < 4; ++r) rs[mt][r] += __shfl_xor(rs[mt][r], o);
    if (lrow == 0) {
        #pragma unroll
        for (int mt = 0; mt < 8; ++mt)
            #pragma unroll
            for (int r = 0; r < 4; ++r)
                sm[w][mt * 16 + lk * 4 + r] = rs[mt][r];
    }
    __syncthreads();
    if (threadIdx.x < 128) {
        float p = sm[0][threadIdx.x] + sm[1][threadIdx.x]
                + sm[2][threadIdx.x] + sm[3][threadIdx.x];
        atomicAdd(&rsum8[(blockIdx.x & 7) * 128 + threadIdx.x], p);
    }
}

// ---------------- vocab MFMA pass 2: recompute logits, scale, write (+pad) -----------
__global__ void k_vwrite(const float* __restrict__ hid, const float* __restrict__ Wov,
                         const float* __restrict__ bov, const float* __restrict__ pgen,
                         const float* __restrict__ rsum8, float* __restrict__ out) {
    __shared__ float scs[128];
    if (blockIdx.x == 391) {     // pad-zero block group: zero out[:, V:V+L)
        for (int i = threadIdx.x; i < B_ * (L_ / 4); i += 256) {
            int b = i >> 7, k = i & 127;
            ((float4*)(out + (size_t)b * VL_ + V_))[k] = make_float4(0.f,0.f,0.f,0.f);
        }
        return;
    }
    if (threadIdx.x < 128) {
        float s = 0.f;
        #pragma unroll
        for (int j = 0; j < 8; ++j) s += rsum8[j * 128 + threadIdx.x];
        scs[threadIdx.x] = pgen[threadIdx.x] / s;
    }
    __syncthreads();
    int L = threadIdx.x & 63, w = threadIdx.x >> 6;
    int lrow = L & 15, lk = L >> 4;
    int n0 = blockIdx.x * 128 + w * 32;

    bf16x8 bfr[2][4];
    #pragma unroll
    for (int nt = 0; nt < 2; ++nt) {
        int n = n0 + nt * 16 + lrow;
        #pragma unroll
        for (int kk = 0; kk < 4; ++kk) {
            bf16x8 f;
            if (n < V_) {
                const float* p = Wov + (size_t)n * 128 + kk * 32 + lk * 8;
                float4 x = *(const float4*)p, y = *(const float4*)(p + 4);
                f[0]=f2bf(x.x); f[1]=f2bf(x.y); f[2]=f2bf(x.z); f[3]=f2bf(x.w);
                f[4]=f2bf(y.x); f[5]=f2bf(y.y); f[6]=f2bf(y.z); f[7]=f2bf(y.w);
            } else {
                #pragma unroll
                for (int j = 0; j < 8; ++j) f[j] = 0;
            }
            bfr[nt][kk] = f;
        }
    }
    f32x4 acc[8][2] = {};
    #pragma unroll
    for (int mt = 0; mt < 8; ++mt) {
        bf16x8 afr[4];
        #pragma unroll
        for (int kk = 0; kk < 4; ++kk) {
            const float* p = hid + (size_t)(mt * 16 + lrow) * 128 + kk * 32 + lk * 8;
            float4 x = *(const float4*)p, y = *(const float4*)(p + 4);
            bf16x8 f;
            f[0]=f2bf(x.x); f[1]=f2bf(x.y); f[2]=f2bf(x.z); f[3]=f2bf(x.w);
            f[4]=f2bf(y.x); f[5]=f2bf(y.y); f[6]=f2bf(y.z); f[7]=f2bf(y.w);
            afr[kk] = f;
        }
        #pragma unroll
        for (int nt = 0; nt < 2; ++nt)
            #pragma unroll
            for (int kk = 0; kk < 4; ++kk)
                acc[mt][nt] = __builtin_amdgcn_mfma_f32_16x16x32_bf16(
                    afr[kk], bfr[nt][kk], acc[mt][nt], 0, 0, 0);
    }
    float bv[2];
    #pragma unroll
    for (int nt = 0; nt < 2; ++nt) {
        int n = n0 + nt * 16 + lrow;
        bv[nt] = (n < V_) ? bov[n] : 0.f;
    }
    #pragma unroll
    for (int mt = 0; mt < 8; ++mt) {
        #pragma unroll
        for (int nt = 0; nt < 2; ++nt) {
            int n = n0 + nt * 16 + lrow;
            if (n < V_) {
                #pragma unroll
                for (int r = 0; r < 4; ++r) {
                    int row = mt * 16 + lk * 4 + r;
                    out[(size_t)row * VL_ + n] =
                        __expf(acc[mt][nt][r] + bv[nt]) * scs[row];
                }
            }
        }
    }
}

// ---------------- scatter copy distribution ----------------
__global__ void k_scatter(float* __restrict__ out, const int* __restrict__ full_input,
                          const float* __restrict__ attn, const float* __restrict__ pgen) {
    int idx = blockIdx.x * blockDim.x + threadIdx.x;  // L*B = 65536
    int b = idx & 127;
    int tok = full_input[idx];
    atomicAdd(&out[(size_t)b * VL_ + tok], (1.f - pgen[b]) * attn[idx]);
}

extern "C" void kernel_launch(void* const* d_in, const int* in_sizes, int n_in,
                              void* d_out, int out_size, void* d_ws, size_t ws_size,
                              hipStream_t stream) {
    const int*   input_ids = (const int*)d_in[0];
    const float* hidden    = (const float*)d_in[1];
    const float* enc       = (const float*)d_in[2];
    const int*   full_in   = (const int*)d_in[3];
    const float* emb_tab   = (const float*)d_in[4];
    const float* W_ih      = (const float*)d_in[5];
    const float* W_hh      = (const float*)d_in[6];
    const float* b_ih      = (const float*)d_in[7];
    const float* b_hh      = (const float*)d_in[8];
    const float* W_ds      = (const float*)d_in[9];
    const float* b_ds      = (const float*)d_in[10];
    const float* w_h       = (const float*)d_in[11];
    const float* att_v     = (const float*)d_in[12];
    const float* W_oh      = (const float*)d_in[13];
    const float* b_oh      = (const float*)d_in[14];
    const float* W_ov      = (const float*)d_in[15];
    const float* b_ov      = (const float*)d_in[16];
    const float* W_ptr     = (const float*)d_in[17];
    const float* b_ptr     = (const float*)d_in[18];

    float* out = (float*)d_out;
    float* p_final = out;                                  // [B, VL]
    float* h_out   = out + (size_t)B_ * VL_;               // [B, H2]
    float* attn    = out + (size_t)B_ * VL_ + B_ * H2_;    // [L, B]

    float* ws = (float*)d_ws;
    float* gxp    = ws;             // 2 * 196608 = 393216
    float* ghp    = gxp + 393216;   // 4 * 196608 = 786432
    float* comb   = ghp + 786432;   // 131072
    float* dslp   = comb + 131072;  // 4 * 65536 = 262144
    float* scores = dslp + 262144;  // 65536
    float* ctxp   = scores + 65536; // 8 * 65536 = 524288
    float* hid    = ctxp + 524288;  // 16384
    float* pgen   = hid + 16384;    // 128
    float* rsum8  = pgen + 128;     // 1024

    // 1. gx & gh gate GEMMs -> partial buffers (no atomics)
    k_gates<<<dim3(4,48,6), dim3(256), 0, stream>>>(input_ids, emb_tab, hidden,
                                                    W_ih, W_hh, gxp, ghp);
    // 2. GRU: reduce partials + biases -> h_new; init hid=b_oh, rsum8=0
    k_gru<<<dim3(256), dim3(256), 0, stream>>>(gxp, ghp, b_ih, b_hh, hidden, b_oh,
                                               comb, h_out, hid, rsum8);
    // 3. dsl partials (split-K 4, plain stores)
    gemm_t<32,32,32,2,2,4,false><<<dim3(4,16,4), dim3(256), 0, stream>>>(
        comb, 2*H2_, W_ds, H2_, dslp, H2_, H2_, H2_, B_*H2_);
    // 4. attention scores (8 l's per wave; dsl summed from partials + b_ds)
    k_scores<<<dim3(2048), dim3(256), 0, stream>>>(enc, dslp, b_ds, w_h, att_v, scores);
    // 5. softmax over batch axis
    k_softmax<<<dim3(L_), dim3(64), 0, stream>>>(scores, attn);
    // 6. context partials (plain stores)
    k_context<<<dim3(B_, 8), dim3(128), 0, stream>>>(enc, attn, ctxp);
    // 7. ctx reduce + p_gen
    k_ctxpgen<<<dim3(B_), dim3(128), 0, stream>>>(ctxp, input_ids, emb_tab,
                                                  W_ptr, b_ptr, comb, pgen);
    // 8. hid = comb @ W_oh^T + b_oh (split-K 8, atomic onto bias init)
    gemm_t<32,32,32,2,2,8,true><<<dim3(4,4,8), dim3(256), 0, stream>>>(
        comb, 2*H2_, W_oh, 2*H2_, hid, E_, E_, 2*H2_, 0);
    // 9. vocab pass 1: rsum8 partials only
    k_vsum<<<dim3(391), dim3(256), 0, stream>>>(hid, W_ov, b_ov, rsum8);
    // 10. vocab pass 2: recompute, scale, write p_final (+ zero pad)
    k_vwrite<<<dim3(392), dim3(256), 0, stream>>>(hid, W_ov, b_ov, pgen, rsum8, p_final);
    // 11. scatter
    k_scatter<<<dim3(L_*B_/256), dim3(256), 0, stream>>>(p_final, full_in, attn, pgen);
}